// Round 9
// baseline (441.769 us; speedup 1.0000x reference)
//
#include <hip/hip_runtime.h>

typedef __attribute__((ext_vector_type(4))) float f32x4;
typedef __attribute__((ext_vector_type(8))) _Float16 f16x8;

#define BM 128
#define BK 64

// workspace layout (bytes)
#define OFF_W0T 0                                   // 512*128*2   = 131072
#define OFF_WT  131072                              // 6*512*1536*2 = 9437184
#define OFF_X0  (OFF_WT + 6*512*1536*2)             // 16384*128*2 = 4194304
#define OFF_Y0  (OFF_X0 + 16384*128*2)              // 16*1056*512*2
#define OFF_Y1  (OFF_Y0 + 16*1056*512*2)

__device__ __forceinline__ void load_lds16(const void* g, void* s) {
    __builtin_amdgcn_global_load_lds(
        (const __attribute__((address_space(1))) void*)g,
        (__attribute__((address_space(3))) void*)s, 16, 0, 0);
}

// ---- weight prep: ws [6][3][512][512] (ci-major in, co inner) -> wt [l][co][t*512+ci] f16
//      w0 [128][512] -> w0t [co][ci] f16
__global__ __launch_bounds__(256)
void wprep(const float* __restrict__ ws, const float* __restrict__ w0,
           _Float16* __restrict__ wt, _Float16* __restrict__ w0t)
{
    __shared__ float t[64][65];
    const int tid = threadIdx.x;
    const int tr = tid >> 6;       // 0..3
    const int tc = tid & 63;
    const int z = blockIdx.z;
    if (z < 18) {
        const int l = z / 3, tp = z % 3;
        const float* src = ws + (size_t)z * 512 * 512;      // [ci][co]
        const int ci0 = blockIdx.y * 64, co0 = blockIdx.x * 64;
        #pragma unroll
        for (int i = 0; i < 16; ++i) { int r = i*4 + tr; t[r][tc] = src[(ci0 + r)*512 + co0 + tc]; }
        __syncthreads();
        _Float16* dst = wt + (size_t)l * 512 * 1536;
        #pragma unroll
        for (int i = 0; i < 16; ++i) { int r = i*4 + tr; dst[(co0 + r)*1536 + tp*512 + ci0 + tc] = (_Float16)t[tc][r]; }
    } else {
        if (blockIdx.y >= 2) return;
        const int ci0 = blockIdx.y * 64, co0 = blockIdx.x * 64;
        #pragma unroll
        for (int i = 0; i < 16; ++i) { int r = i*4 + tr; t[r][tc] = w0[(ci0 + r)*512 + co0 + tc]; }
        __syncthreads();
        #pragma unroll
        for (int i = 0; i < 16; ++i) { int r = i*4 + tr; w0t[(co0 + r)*128 + ci0 + tc] = (_Float16)t[tc][r]; }
    }
}

// ---- zero the 16-row pads of both activation buffers (as u32)
__global__ __launch_bounds__(256)
void zeropad(_Float16* __restrict__ Y0, _Float16* __restrict__ Y1)
{
    const int i = blockIdx.x * 256 + threadIdx.x;       // 262144 total
    const unsigned c2   = i & 255;                      // u32 col (512 f16 / row)
    const unsigned t2   = ((unsigned)i) >> 8;
    const unsigned prow = t2 & 31;
    const unsigned b    = (t2 >> 5) & 15;
    const unsigned buf  = t2 >> 9;
    const unsigned row  = prow < 16 ? prow : (1024 + prow); // [0,16) and [1040,1056)
    unsigned* p = (unsigned*)(buf ? Y1 : Y0);
    p[((size_t)b * 1056 + row) * 256 + c2] = 0u;
}

// ---- bilinear sample + concat -> X0 [16384][128] f16
__global__ __launch_bounds__(256)
void sample_kernel(const float* __restrict__ verts, const float* __restrict__ fm,
                   _Float16* __restrict__ X0)
{
    const int p = blockIdx.x * 4 + (threadIdx.x >> 6);  // 0..16383
    const int lane = threadIdx.x & 63;
    const int b = p >> 10;
    const float vy = verts[p*2], vx = verts[p*2 + 1];
    const float cy = (vy + 1.f) * 127.5f;
    const float cx = (vx + 1.f) * 127.5f;
    const float fy = floorf(cy), fx = floorf(cx);
    const int y0 = (int)fy, x0 = (int)fx;
    const float wy = cy - fy, wx = cx - fx;
    float w00 = (1.f - wy) * (1.f - wx), w01 = (1.f - wy) * wx;
    float w10 = wy * (1.f - wx),         w11 = wy * wx;
    const bool vy0 = (unsigned)y0 < 256u, vy1 = (unsigned)(y0 + 1) < 256u;
    const bool vx0 = (unsigned)x0 < 256u, vx1 = (unsigned)(x0 + 1) < 256u;
    w00 = (vy0 && vx0) ? w00 : 0.f;
    w01 = (vy0 && vx1) ? w01 : 0.f;
    w10 = (vy1 && vx0) ? w10 : 0.f;
    w11 = (vy1 && vx1) ? w11 : 0.f;
    const int yc0 = min(max(y0, 0), 255), yc1 = min(max(y0 + 1, 0), 255);
    const int xc0 = min(max(x0, 0), 255), xc1 = min(max(x0 + 1, 0), 255);
    const float* base = fm + (size_t)b * (256 * 256 * 126);
    const float* p00 = base + (yc0 * 256 + xc0) * 126;
    const float* p01 = base + (yc0 * 256 + xc1) * 126;
    const float* p10 = base + (yc1 * 256 + xc0) * 126;
    const float* p11 = base + (yc1 * 256 + xc1) * 126;
    _Float16* xr = X0 + (size_t)p * 128;
    for (int c = lane; c < 126; c += 64) {
        float a = w00 * p00[c] + w01 * p01[c] + w10 * p10[c] + w11 * p11[c];
        xr[c] = (_Float16)a;
    }
    if (lane < 2) xr[126 + lane] = (_Float16)(lane ? vx : vy);
}

// ---- layer-0 GEMM (K=128), m97 structure, 128x128 tile
template<int KTOT>
__global__ __launch_bounds__(256)
void conv_gemm(const _Float16* __restrict__ A, int a_row_stride, int a_batch_stride,
               const _Float16* __restrict__ WT, const float* __restrict__ bias,
               _Float16* __restrict__ Out, int o_row_stride, int o_batch_stride,
               int dil)
{
    __shared__ _Float16 Ald[BM * BK];
    __shared__ _Float16 Bld[BM * BK];
    const int tid  = threadIdx.x;
    const int wid  = tid >> 6;
    const int lane = tid & 63;
    const int b    = blockIdx.x >> 3;
    const int n0   = (blockIdx.x & 7) * BM;
    const int co0  = blockIdx.y * BM;
    const int wm   = wid >> 1, wn = wid & 1;

    const _Float16* Ab = A + (size_t)b * a_batch_stride + (size_t)n0 * a_row_stride;

    f32x4 acc[4][4] = {};

    const int srow = lane >> 3;
    const int scol = (lane & 7) * 8;

    for (int ks = 0; ks < KTOT / BK; ++ks) {
        int ci0, shift;
        if (KTOT == 128) { ci0 = ks * 64; shift = 0; }
        else             { int t = ks >> 3; ci0 = (ks & 7) * 64; shift = (t - 1) * dil; }
        const _Float16* Arow = Ab + (long)shift * a_row_stride + ci0 + scol;
        const _Float16* Brow = WT + (size_t)co0 * KTOT + ks * 64 + scol;
        #pragma unroll
        for (int i = 0; i < 4; ++i) {
            const int r0 = wid * 32 + i * 8;
            load_lds16(Arow + (size_t)(r0 + srow) * a_row_stride, &Ald[r0 * BK]);
            load_lds16(Brow + (size_t)(r0 + srow) * KTOT,         &Bld[r0 * BK]);
        }
        __syncthreads();
        #pragma unroll
        for (int kf = 0; kf < 2; ++kf) {
            f16x8 af[4], bfr[4];
            #pragma unroll
            for (int f = 0; f < 4; ++f) {
                af[f]  = *(const f16x8*)&Ald[(wm*64 + f*16 + (lane & 15)) * BK + kf*32 + (lane >> 4) * 8];
                bfr[f] = *(const f16x8*)&Bld[(wn*64 + f*16 + (lane & 15)) * BK + kf*32 + (lane >> 4) * 8];
            }
            #pragma unroll
            for (int m = 0; m < 4; ++m)
                #pragma unroll
                for (int n = 0; n < 4; ++n)
                    acc[m][n] = __builtin_amdgcn_mfma_f32_16x16x32_f16(af[m], bfr[n], acc[m][n], 0, 0, 0);
        }
        __syncthreads();
    }

    _Float16* Ob = Out + (size_t)b * o_batch_stride + (size_t)n0 * o_row_stride;
    #pragma unroll
    for (int n = 0; n < 4; ++n) {
        const int co = co0 + wn*64 + n*16 + (lane & 15);
        const float bv = bias[co];
        #pragma unroll
        for (int m = 0; m < 4; ++m) {
            #pragma unroll
            for (int j = 0; j < 4; ++j) {
                const int row = wm*64 + m*16 + (lane >> 4)*4 + j;
                float v = acc[m][n][j] + bv;
                v = fmaxf(v, 0.f);
                Ob[(size_t)row * o_row_stride + co] = (_Float16)v;
            }
        }
    }
}

// ---- mid-layer GEMM (r9): r8 structure (8 waves 4Mx2N, block 256x128, BK=64,
// single barrier/tile, T2 swizzle on A) with B read DIRECTLY from global
// (L1/L2-resident weights) as per-lane global_load_dwordx4 fragments — no B
// staging, no B LDS reads. LDS: 3-deep A only (96 KB). VMEM order per body:
// {8 B-loads, 4 A-stages} pinned by sched_barrier -> uniform vmcnt(4) at top.
#define NT8 24
__global__ __launch_bounds__(512, 2)
void conv_gemm8(const _Float16* __restrict__ A, const _Float16* __restrict__ WT,
                const float* __restrict__ bias, _Float16* __restrict__ Out, int dil)
{
    extern __shared__ _Float16 smem[];
    _Float16* Ald = smem;                 // [3][256*64]

    const int tid  = threadIdx.x;
    const int wid  = tid >> 6;
    const int lane = tid & 63;
    const int wm   = wid >> 1;            // 0..3 : 64-row band
    const int wn   = wid & 1;             // 0..1 : 64-col half

    // XCD-aware bijective swizzle (256 blocks, 256%8==0)
    const int orig = blockIdx.x;
    const int swz  = (orig & 7) * 32 + (orig >> 3);
    const int nblk = swz & 3;
    const int mblk = swz >> 2;
    const int b     = mblk >> 2;
    const int n0row = (mblk & 3) * 256;
    const int co0   = nblk * 128;

    const _Float16* Ab = A + (size_t)b * (1056 * 512) + (size_t)n0row * 512;

    // A staging: chunk = 64 rows x 64 k (8KB); wave w covers rows 8w..8w+7
    const int srow = lane >> 3;                              // row within wave's 8
    const int scol = (((lane & 7) ^ (lane >> 3)) << 3);      // pre-swizzled global col (f16)

    // B: per-lane fragment base in WT (rows = co, 1536 f16/row)
    const _Float16* WB = WT + (size_t)(co0 + wn * 64 + (lane & 15)) * 1536 + (lane >> 4) * 8;

    f32x4 acc[4][4] = {};

    auto stageA = [&](int kt, int c, int ci0, int shift) {
        const int grow = 64 * c + 8 * wid + srow;
        const _Float16* src = Ab + (long)(grow + shift) * 512 + ci0 + scol;
        _Float16* dst = Ald + (kt % 3) * (256 * 64) + (64 * c + 8 * wid) * 64;
        load_lds16(src, dst);
    };
    auto kinfo = [&](int ks, int& ci0, int& shift) {
        const int t = ks >> 3; ci0 = (ks & 7) * 64; shift = (t - 1) * dil;
    };

    // prologue: stage A for tiles 0 and 1 (4 loads each per wave)
    {
        int ci0, sh;
        kinfo(0, ci0, sh);
        stageA(0, 0, ci0, sh); stageA(0, 1, ci0, sh); stageA(0, 2, ci0, sh); stageA(0, 3, ci0, sh);
        kinfo(1, ci0, sh);
        stageA(1, 0, ci0, sh); stageA(1, 1, ci0, sh); stageA(1, 2, ci0, sh); stageA(1, 3, ci0, sh);
    }

    for (int kt = 0; kt < NT8; ++kt) {
        // invariant: outstanding VMEM here = 4 newest (A stages of kt+1);
        // A(kt) already landed (retired by compiler's pre-MFMA wait last iter)
        __builtin_amdgcn_sched_barrier(0);
        asm volatile("s_waitcnt vmcnt(4)" ::: "memory");
        __builtin_amdgcn_s_barrier();
        __builtin_amdgcn_sched_barrier(0);

        // B fragments for this tile, straight from global (L1-resident slice)
        f16x8 bfr[4][2];
        #pragma unroll
        for (int nf = 0; nf < 4; ++nf)
            #pragma unroll
            for (int kf = 0; kf < 2; ++kf)
                bfr[nf][kf] = *(const f16x8*)(WB + nf * 16 * 1536 + kt * 64 + kf * 32);
        __builtin_amdgcn_sched_barrier(0);   // pin: all B loads precede A stages in VMEM order

        const _Float16* Abuf = Ald + (kt % 3) * (256 * 64);
        f16x8 af[4][2];
        #pragma unroll
        for (int mf = 0; mf < 4; ++mf) {
            const int row = wm * 64 + mf * 16 + (lane & 15);
            #pragma unroll
            for (int kf = 0; kf < 2; ++kf) {
                const int slot = (kf * 4 + (lane >> 4)) ^ (row & 7);
                af[mf][kf] = *(const f16x8*)&Abuf[row * 64 + slot * 8];
            }
        }
        if (kt + 2 < NT8) {
            int nci0, nsh; kinfo(kt + 2, nci0, nsh);
            stageA(kt + 2, 0, nci0, nsh);
            stageA(kt + 2, 1, nci0, nsh);
            stageA(kt + 2, 2, nci0, nsh);
            stageA(kt + 2, 3, nci0, nsh);
        }
        __builtin_amdgcn_sched_barrier(0);   // pin: stages issued before MFMA cluster

        __builtin_amdgcn_s_setprio(1);
        #pragma unroll
        for (int mf = 0; mf < 4; ++mf)
            #pragma unroll
            for (int nf = 0; nf < 4; ++nf)
                #pragma unroll
                for (int kf = 0; kf < 2; ++kf)
                    acc[mf][nf] = __builtin_amdgcn_mfma_f32_16x16x32_f16(
                        af[mf][kf], bfr[nf][kf], acc[mf][nf], 0, 0, 0);
        __builtin_amdgcn_s_setprio(0);
    }

    _Float16* Ob = Out + (size_t)b * (1056 * 512) + (size_t)n0row * 512;
    #pragma unroll
    for (int nf = 0; nf < 4; ++nf) {
        const int co = co0 + wn * 64 + nf * 16 + (lane & 15);
        const float bv = bias[co];
        #pragma unroll
        for (int m = 0; m < 4; ++m) {
            #pragma unroll
            for (int j = 0; j < 4; ++j) {
                const int row = wm * 64 + m * 16 + (lane >> 4) * 4 + j;
                float v = acc[m][nf][j] + bv;
                v = fmaxf(v, 0.f);
                Ob[(size_t)row * 512 + co] = (_Float16)v;
            }
        }
    }
}

// ---- final 1x1 conv to 2 channels, fp32 out. One wave per row.
__global__ __launch_bounds__(256)
void final_conv(const _Float16* __restrict__ Y, const float* __restrict__ woff,
                float* __restrict__ out)
{
    const int r = blockIdx.x * 4 + (threadIdx.x >> 6);  // 0..16383
    const int lane = threadIdx.x & 63;
    const int b = r >> 10, n = r & 1023;
    const _Float16* yp = Y + ((size_t)b * 1056 + n) * 512 + lane * 8;
    f16x8 yv = *(const f16x8*)yp;
    const int ci0 = lane * 8;
    float s0 = 0.f, s1 = 0.f;
    #pragma unroll
    for (int e = 0; e < 8; ++e) {
        float y = (float)yv[e];
        s0 += y * woff[(ci0 + e) * 2 + 0];
        s1 += y * woff[(ci0 + e) * 2 + 1];
    }
    #pragma unroll
    for (int off = 32; off; off >>= 1) {
        s0 += __shfl_down(s0, off);
        s1 += __shfl_down(s1, off);
    }
    if (lane == 0) { out[r*2] = s0; out[r*2 + 1] = s1; }
}

extern "C" void kernel_launch(void* const* d_in, const int* in_sizes, int n_in,
                              void* d_out, int out_size, void* d_ws, size_t ws_size,
                              hipStream_t stream)
{
    const float* verts = (const float*)d_in[0];
    const float* fm    = (const float*)d_in[1];
    const float* w0    = (const float*)d_in[2];
    const float* b0    = (const float*)d_in[3];
    const float* ws    = (const float*)d_in[4];
    const float* bs    = (const float*)d_in[5];
    const float* woff  = (const float*)d_in[6];
    float* out = (float*)d_out;

    char* wsp = (char*)d_ws;
    _Float16* W0T = (_Float16*)(wsp + OFF_W0T);
    _Float16* WT  = (_Float16*)(wsp + OFF_WT);
    _Float16* X0  = (_Float16*)(wsp + OFF_X0);
    _Float16* Y0  = (_Float16*)(wsp + OFF_Y0);
    _Float16* Y1  = (_Float16*)(wsp + OFF_Y1);
    _Float16* Y0i = Y0 + 16 * 512;   // interior (row 0 of batch 0)
    _Float16* Y1i = Y1 + 16 * 512;

    hipFuncSetAttribute(reinterpret_cast<const void*>(&conv_gemm8),
                        hipFuncAttributeMaxDynamicSharedMemorySize, 98304);

    wprep<<<dim3(8, 8, 19), 256, 0, stream>>>(ws, w0, WT, W0T);
    zeropad<<<1024, 256, 0, stream>>>(Y0, Y1);
    sample_kernel<<<4096, 256, 0, stream>>>(verts, fm, X0);

    // layer 0: 1x1 conv, K=128 (old structure, small K)
    conv_gemm<128><<<dim3(128, 4), 256, 0, stream>>>(
        X0, 128, 1024 * 128, W0T, b0, Y0i, 512, 1056 * 512, 1);

    // 6 dilated mid layers, K=1536, r9 kernel
    const int DIL[6] = {1, 3, 9, 9, 3, 1};
    _Float16* bufs[2] = {Y0i, Y1i};
    for (int l = 0; l < 6; ++l) {
        conv_gemm8<<<256, 512, 98304, stream>>>(
            bufs[l & 1],
            WT + (size_t)l * 512 * 1536, bs + (size_t)l * 512,
            bufs[(l + 1) & 1], DIL[l]);
    }

    // final projection (reads Y0i after 6 layers)
    final_conv<<<4096, 256, 0, stream>>>(bufs[0], woff, out);
}

// Round 10
// 225.029 us; speedup vs baseline: 1.9632x; 1.9632x over previous
//
#include <hip/hip_runtime.h>

typedef __attribute__((ext_vector_type(4))) float f32x4;
typedef __attribute__((ext_vector_type(8))) _Float16 f16x8;

#define BM 128
#define BK 64

// workspace layout (bytes)
#define OFF_W0T 0                                   // 512*128*2   = 131072
#define OFF_WT  131072                              // 6*512*1536*2 = 9437184 (packed fragment-major)
#define OFF_X0  (OFF_WT + 6*512*1536*2)             // 16384*128*2 = 4194304
#define OFF_Y0  (OFF_X0 + 16384*128*2)              // 16*1056*512*2
#define OFF_Y1  (OFF_Y0 + 16*1056*512*2)

__device__ __forceinline__ void load_lds16(const void* g, void* s) {
    __builtin_amdgcn_global_load_lds(
        (const __attribute__((address_space(1))) void*)g,
        (__attribute__((address_space(3))) void*)s, 16, 0, 0);
}

// ---- weight prep:
//  mid layers: ws [6][3][512][512] ([ci][co]) -> packed fragment-major
//    wtp[l][cot][kt][nf*2+kf][chunk=k8*16+colo][8]  (chunk==lane in the GEMM)
//    where k = tap*512 + ci ; kt=k>>6 ; kf=(ci>>5)&1 ; k8=(ci>>3)&3 ; e=ci&7
//          co = cot*64 + nf*16 + colo
//  layer0: w0 [128][512] -> w0t [co][ci] f16 (unchanged)
__global__ __launch_bounds__(256)
void wprep(const float* __restrict__ ws, const float* __restrict__ w0,
           _Float16* __restrict__ wtp, _Float16* __restrict__ w0t)
{
    __shared__ float t[64][65];
    const int tid = threadIdx.x;
    const int tr = tid >> 6;       // 0..3
    const int tc = tid & 63;
    const int z = blockIdx.z;
    if (z < 18) {
        const int l = z / 3, tap = z % 3;
        const float* src = ws + (size_t)z * 512 * 512;      // [ci][co]
        const int ci0 = blockIdx.y * 64, co0 = blockIdx.x * 64;
        #pragma unroll
        for (int i = 0; i < 16; ++i) { int r = i*4 + tr; t[r][tc] = src[(ci0 + r)*512 + co0 + tc]; }
        __syncthreads();
        // t[ci_local][co_local]
        const int kt = tap * 8 + blockIdx.y;                // K-tile index (64-wide)
        _Float16* dst = wtp + (size_t)l * 786432 + ((size_t)blockIdx.x * 24 + kt) * 4096;
        #pragma unroll
        for (int cc = 0; cc < 2; ++cc) {
            const int c2 = tid + cc * 256;                  // 0..511 chunk id
            const int nf   = c2 >> 7;
            const int kf   = (c2 >> 6) & 1;
            const int k8   = (c2 >> 4) & 3;
            const int colo = c2 & 15;
            const int co   = nf * 16 + colo;
            const int cib  = kf * 32 + k8 * 8;
            f16x8 v;
            #pragma unroll
            for (int e = 0; e < 8; ++e) v[e] = (_Float16)t[cib + e][co];
            *(f16x8*)(dst + (size_t)(nf * 2 + kf) * 512 + (k8 * 16 + colo) * 8) = v;
        }
    } else {
        if (blockIdx.y >= 2) return;
        const int ci0 = blockIdx.y * 64, co0 = blockIdx.x * 64;
        #pragma unroll
        for (int i = 0; i < 16; ++i) { int r = i*4 + tr; t[r][tc] = w0[(ci0 + r)*512 + co0 + tc]; }
        __syncthreads();
        #pragma unroll
        for (int i = 0; i < 16; ++i) { int r = i*4 + tr; w0t[(co0 + r)*128 + ci0 + tc] = (_Float16)t[tc][r]; }
    }
}

// ---- zero the 16-row pads of both activation buffers (as u32)
__global__ __launch_bounds__(256)
void zeropad(_Float16* __restrict__ Y0, _Float16* __restrict__ Y1)
{
    const int i = blockIdx.x * 256 + threadIdx.x;       // 262144 total
    const unsigned c2   = i & 255;                      // u32 col (512 f16 / row)
    const unsigned t2   = ((unsigned)i) >> 8;
    const unsigned prow = t2 & 31;
    const unsigned b    = (t2 >> 5) & 15;
    const unsigned buf  = t2 >> 9;
    const unsigned row  = prow < 16 ? prow : (1024 + prow); // [0,16) and [1040,1056)
    unsigned* p = (unsigned*)(buf ? Y1 : Y0);
    p[((size_t)b * 1056 + row) * 256 + c2] = 0u;
}

// ---- bilinear sample + concat -> X0 [16384][128] f16
__global__ __launch_bounds__(256)
void sample_kernel(const float* __restrict__ verts, const float* __restrict__ fm,
                   _Float16* __restrict__ X0)
{
    const int p = blockIdx.x * 4 + (threadIdx.x >> 6);  // 0..16383
    const int lane = threadIdx.x & 63;
    const int b = p >> 10;
    const float vy = verts[p*2], vx = verts[p*2 + 1];
    const float cy = (vy + 1.f) * 127.5f;
    const float cx = (vx + 1.f) * 127.5f;
    const float fy = floorf(cy), fx = floorf(cx);
    const int y0 = (int)fy, x0 = (int)fx;
    const float wy = cy - fy, wx = cx - fx;
    float w00 = (1.f - wy) * (1.f - wx), w01 = (1.f - wy) * wx;
    float w10 = wy * (1.f - wx),         w11 = wy * wx;
    const bool vy0 = (unsigned)y0 < 256u, vy1 = (unsigned)(y0 + 1) < 256u;
    const bool vx0 = (unsigned)x0 < 256u, vx1 = (unsigned)(x0 + 1) < 256u;
    w00 = (vy0 && vx0) ? w00 : 0.f;
    w01 = (vy0 && vx1) ? w01 : 0.f;
    w10 = (vy1 && vx0) ? w10 : 0.f;
    w11 = (vy1 && vx1) ? w11 : 0.f;
    const int yc0 = min(max(y0, 0), 255), yc1 = min(max(y0 + 1, 0), 255);
    const int xc0 = min(max(x0, 0), 255), xc1 = min(max(x0 + 1, 0), 255);
    const float* base = fm + (size_t)b * (256 * 256 * 126);
    const float* p00 = base + (yc0 * 256 + xc0) * 126;
    const float* p01 = base + (yc0 * 256 + xc1) * 126;
    const float* p10 = base + (yc1 * 256 + xc0) * 126;
    const float* p11 = base + (yc1 * 256 + xc1) * 126;
    _Float16* xr = X0 + (size_t)p * 128;
    for (int c = lane; c < 126; c += 64) {
        float a = w00 * p00[c] + w01 * p01[c] + w10 * p10[c] + w11 * p11[c];
        xr[c] = (_Float16)a;
    }
    if (lane < 2) xr[126 + lane] = (_Float16)(lane ? vx : vy);
}

// ---- layer-0 GEMM (K=128), m97 structure, 128x128 tile
template<int KTOT>
__global__ __launch_bounds__(256)
void conv_gemm(const _Float16* __restrict__ A, int a_row_stride, int a_batch_stride,
               const _Float16* __restrict__ WT, const float* __restrict__ bias,
               _Float16* __restrict__ Out, int o_row_stride, int o_batch_stride,
               int dil)
{
    __shared__ _Float16 Ald[BM * BK];
    __shared__ _Float16 Bld[BM * BK];
    const int tid  = threadIdx.x;
    const int wid  = tid >> 6;
    const int lane = tid & 63;
    const int b    = blockIdx.x >> 3;
    const int n0   = (blockIdx.x & 7) * BM;
    const int co0  = blockIdx.y * BM;
    const int wm   = wid >> 1, wn = wid & 1;

    const _Float16* Ab = A + (size_t)b * a_batch_stride + (size_t)n0 * a_row_stride;

    f32x4 acc[4][4] = {};

    const int srow = lane >> 3;
    const int scol = (lane & 7) * 8;

    for (int ks = 0; ks < KTOT / BK; ++ks) {
        int ci0, shift;
        if (KTOT == 128) { ci0 = ks * 64; shift = 0; }
        else             { int t = ks >> 3; ci0 = (ks & 7) * 64; shift = (t - 1) * dil; }
        const _Float16* Arow = Ab + (long)shift * a_row_stride + ci0 + scol;
        const _Float16* Brow = WT + (size_t)co0 * KTOT + ks * 64 + scol;
        #pragma unroll
        for (int i = 0; i < 4; ++i) {
            const int r0 = wid * 32 + i * 8;
            load_lds16(Arow + (size_t)(r0 + srow) * a_row_stride, &Ald[r0 * BK]);
            load_lds16(Brow + (size_t)(r0 + srow) * KTOT,         &Bld[r0 * BK]);
        }
        __syncthreads();
        #pragma unroll
        for (int kf = 0; kf < 2; ++kf) {
            f16x8 af[4], bfr[4];
            #pragma unroll
            for (int f = 0; f < 4; ++f) {
                af[f]  = *(const f16x8*)&Ald[(wm*64 + f*16 + (lane & 15)) * BK + kf*32 + (lane >> 4) * 8];
                bfr[f] = *(const f16x8*)&Bld[(wn*64 + f*16 + (lane & 15)) * BK + kf*32 + (lane >> 4) * 8];
            }
            #pragma unroll
            for (int m = 0; m < 4; ++m)
                #pragma unroll
                for (int n = 0; n < 4; ++n)
                    acc[m][n] = __builtin_amdgcn_mfma_f32_16x16x32_f16(af[m], bfr[n], acc[m][n], 0, 0, 0);
        }
        __syncthreads();
    }

    _Float16* Ob = Out + (size_t)b * o_batch_stride + (size_t)n0 * o_row_stride;
    #pragma unroll
    for (int n = 0; n < 4; ++n) {
        const int co = co0 + wn*64 + n*16 + (lane & 15);
        const float bv = bias[co];
        #pragma unroll
        for (int m = 0; m < 4; ++m) {
            #pragma unroll
            for (int j = 0; j < 4; ++j) {
                const int row = wm*64 + m*16 + (lane >> 4)*4 + j;
                float v = acc[m][n][j] + bv;
                v = fmaxf(v, 0.f);
                Ob[(size_t)row * o_row_stride + co] = (_Float16)v;
            }
        }
    }
}

// ---- mid-layer GEMM (r10): r8 structure (8 waves 4Mx2N, block 256x128, BK=64,
// single barrier/tile, T2 swizzle on A, 3-deep A pipeline) with B read from
// global in PACKED fragment-major layout (coalesced lane*16B bursts), one-tile
// prefetched into the SAME bfr registers after the MFMA cluster (WAR-safe).
// VMEM/body order: [A stages kt+2 (4)] then [B kt+1 (8)] -> top-of-loop
// outstanding = 12 -> vmcnt(12) retires A(kt) exactly.
#define NT8 24
__global__ __launch_bounds__(512, 2)
void conv_gemm8(const _Float16* __restrict__ A, const _Float16* __restrict__ WTP,
                const float* __restrict__ bias, _Float16* __restrict__ Out, int dil)
{
    extern __shared__ _Float16 smem[];
    _Float16* Ald = smem;                 // [3][256*64]

    const int tid  = threadIdx.x;
    const int wid  = tid >> 6;
    const int lane = tid & 63;
    const int wm   = wid >> 1;            // 0..3 : 64-row band
    const int wn   = wid & 1;             // 0..1 : 64-col half

    // XCD-aware bijective swizzle (256 blocks, 256%8==0)
    const int orig = blockIdx.x;
    const int swz  = (orig & 7) * 32 + (orig >> 3);
    const int nblk = swz & 3;
    const int mblk = swz >> 2;
    const int b     = mblk >> 2;
    const int n0row = (mblk & 3) * 256;
    const int co0   = nblk * 128;

    const _Float16* Ab = A + (size_t)b * (1056 * 512) + (size_t)n0row * 512;

    // A staging: chunk = 64 rows x 64 k (8KB); wave w covers rows 8w..8w+7
    const int srow = lane >> 3;                              // row within wave's 8
    const int scol = (((lane & 7) ^ (lane >> 3)) << 3);      // pre-swizzled global col (f16)

    // B packed base for this wave's 64-co slice: chunk==lane
    const int cot = nblk * 2 + wn;                           // 0..7
    const _Float16* WB = WTP + (size_t)cot * 24 * 4096 + lane * 8;

    f32x4 acc[4][4] = {};
    f16x8 bfr[4][2];

    auto stageA = [&](int kt, int c, int ci0, int shift) {
        const int grow = 64 * c + 8 * wid + srow;
        const _Float16* src = Ab + (long)(grow + shift) * 512 + ci0 + scol;
        _Float16* dst = Ald + (kt % 3) * (256 * 64) + (64 * c + 8 * wid) * 64;
        load_lds16(src, dst);
    };
    auto kinfo = [&](int ks, int& ci0, int& shift) {
        const int t = ks >> 3; ci0 = (ks & 7) * 64; shift = (t - 1) * dil;
    };
    auto loadB = [&](int kt) {
        const _Float16* base = WB + (size_t)kt * 4096;
        #pragma unroll
        for (int nf = 0; nf < 4; ++nf)
            #pragma unroll
            for (int kf = 0; kf < 2; ++kf)
                bfr[nf][kf] = *(const f16x8*)(base + (nf * 2 + kf) * 512);
    };

    // prologue: stage A tiles 0,1 (4 each), then B(0) (8) -> outstanding 16
    {
        int ci0, sh;
        kinfo(0, ci0, sh);
        stageA(0, 0, ci0, sh); stageA(0, 1, ci0, sh); stageA(0, 2, ci0, sh); stageA(0, 3, ci0, sh);
        kinfo(1, ci0, sh);
        stageA(1, 0, ci0, sh); stageA(1, 1, ci0, sh); stageA(1, 2, ci0, sh); stageA(1, 3, ci0, sh);
        loadB(0);
    }

    for (int kt = 0; kt < NT8; ++kt) {
        // outstanding here: A-stages(kt+1)=4 + B(kt)=8 (kt=0: stages(0..1)=8 + B(0)=8,
        // A(0) older than newest 12 either way) -> vmcnt(12) retires A(kt)
        __builtin_amdgcn_sched_barrier(0);
        asm volatile("s_waitcnt vmcnt(12)" ::: "memory");
        __builtin_amdgcn_s_barrier();
        __builtin_amdgcn_sched_barrier(0);

        const _Float16* Abuf = Ald + (kt % 3) * (256 * 64);
        f16x8 af[4][2];
        #pragma unroll
        for (int mf = 0; mf < 4; ++mf) {
            const int row = wm * 64 + mf * 16 + (lane & 15);
            #pragma unroll
            for (int kf = 0; kf < 2; ++kf) {
                const int slot = (kf * 4 + (lane >> 4)) ^ (row & 7);
                af[mf][kf] = *(const f16x8*)&Abuf[row * 64 + slot * 8];
            }
        }
        if (kt + 2 < NT8) {
            int nci0, nsh; kinfo(kt + 2, nci0, nsh);
            stageA(kt + 2, 0, nci0, nsh);
            stageA(kt + 2, 1, nci0, nsh);
            stageA(kt + 2, 2, nci0, nsh);
            stageA(kt + 2, 3, nci0, nsh);
        }
        __builtin_amdgcn_sched_barrier(0);   // stages pinned before MFMA cluster

        __builtin_amdgcn_s_setprio(1);
        #pragma unroll
        for (int mf = 0; mf < 4; ++mf)
            #pragma unroll
            for (int nf = 0; nf < 4; ++nf)
                #pragma unroll
                for (int kf = 0; kf < 2; ++kf)
                    acc[mf][nf] = __builtin_amdgcn_mfma_f32_16x16x32_f16(
                        af[mf][kf], bfr[nf][kf], acc[mf][nf], 0, 0, 0);
        __builtin_amdgcn_s_setprio(0);

        // prefetch B(kt+1) into the same registers (issued after the MFMAs that
        // read bfr -> WAR-safe; lands during next body's A-read phase)
        if (kt + 1 < NT8) loadB(kt + 1);
    }

    _Float16* Ob = Out + (size_t)b * (1056 * 512) + (size_t)n0row * 512;
    #pragma unroll
    for (int nf = 0; nf < 4; ++nf) {
        const int co = co0 + wn * 64 + nf * 16 + (lane & 15);
        const float bv = bias[co];
        #pragma unroll
        for (int m = 0; m < 4; ++m) {
            #pragma unroll
            for (int j = 0; j < 4; ++j) {
                const int row = wm * 64 + m * 16 + (lane >> 4) * 4 + j;
                float v = acc[m][nf][j] + bv;
                v = fmaxf(v, 0.f);
                Ob[(size_t)row * 512 + co] = (_Float16)v;
            }
        }
    }
}

// ---- final 1x1 conv to 2 channels, fp32 out. One wave per row.
__global__ __launch_bounds__(256)
void final_conv(const _Float16* __restrict__ Y, const float* __restrict__ woff,
                float* __restrict__ out)
{
    const int r = blockIdx.x * 4 + (threadIdx.x >> 6);  // 0..16383
    const int lane = threadIdx.x & 63;
    const int b = r >> 10, n = r & 1023;
    const _Float16* yp = Y + ((size_t)b * 1056 + n) * 512 + lane * 8;
    f16x8 yv = *(const f16x8*)yp;
    const int ci0 = lane * 8;
    float s0 = 0.f, s1 = 0.f;
    #pragma unroll
    for (int e = 0; e < 8; ++e) {
        float y = (float)yv[e];
        s0 += y * woff[(ci0 + e) * 2 + 0];
        s1 += y * woff[(ci0 + e) * 2 + 1];
    }
    #pragma unroll
    for (int off = 32; off; off >>= 1) {
        s0 += __shfl_down(s0, off);
        s1 += __shfl_down(s1, off);
    }
    if (lane == 0) { out[r*2] = s0; out[r*2 + 1] = s1; }
}

extern "C" void kernel_launch(void* const* d_in, const int* in_sizes, int n_in,
                              void* d_out, int out_size, void* d_ws, size_t ws_size,
                              hipStream_t stream)
{
    const float* verts = (const float*)d_in[0];
    const float* fm    = (const float*)d_in[1];
    const float* w0    = (const float*)d_in[2];
    const float* b0    = (const float*)d_in[3];
    const float* ws    = (const float*)d_in[4];
    const float* bs    = (const float*)d_in[5];
    const float* woff  = (const float*)d_in[6];
    float* out = (float*)d_out;

    char* wsp = (char*)d_ws;
    _Float16* W0T = (_Float16*)(wsp + OFF_W0T);
    _Float16* WTP = (_Float16*)(wsp + OFF_WT);   // packed fragment-major
    _Float16* X0  = (_Float16*)(wsp + OFF_X0);
    _Float16* Y0  = (_Float16*)(wsp + OFF_Y0);
    _Float16* Y1  = (_Float16*)(wsp + OFF_Y1);
    _Float16* Y0i = Y0 + 16 * 512;   // interior (row 0 of batch 0)
    _Float16* Y1i = Y1 + 16 * 512;

    hipFuncSetAttribute(reinterpret_cast<const void*>(&conv_gemm8),
                        hipFuncAttributeMaxDynamicSharedMemorySize, 98304);

    wprep<<<dim3(8, 8, 19), 256, 0, stream>>>(ws, w0, WTP, W0T);
    zeropad<<<1024, 256, 0, stream>>>(Y0, Y1);
    sample_kernel<<<4096, 256, 0, stream>>>(verts, fm, X0);

    // layer 0: 1x1 conv, K=128 (old structure, small K)
    conv_gemm<128><<<dim3(128, 4), 256, 0, stream>>>(
        X0, 128, 1024 * 128, W0T, b0, Y0i, 512, 1056 * 512, 1);

    // 6 dilated mid layers, K=1536, r10 kernel
    const int DIL[6] = {1, 3, 9, 9, 3, 1};
    _Float16* bufs[2] = {Y0i, Y1i};
    for (int l = 0; l < 6; ++l) {
        conv_gemm8<<<256, 512, 98304, stream>>>(
            bufs[l & 1],
            WTP + (size_t)l * 786432, bs + (size_t)l * 512,
            bufs[(l + 1) & 1], DIL[l]);
    }

    // final projection (reads Y0i after 6 layers)
    final_conv<<<4096, 256, 0, stream>>>(bufs[0], woff, out);
}

// Round 11
// 202.283 us; speedup vs baseline: 2.1839x; 1.1124x over previous
//
#include <hip/hip_runtime.h>

typedef __attribute__((ext_vector_type(4))) float f32x4;
typedef __attribute__((ext_vector_type(8))) _Float16 f16x8;

#define BM 128
#define BK 64

// workspace layout (bytes)
#define OFF_W0T 0                                   // 512*128*2   = 131072
#define OFF_WT  131072                              // 6*512*1536*2 = 9437184
#define OFF_X0  (OFF_WT + 6*512*1536*2)             // 16384*128*2 = 4194304
#define OFF_Y0  (OFF_X0 + 16384*128*2)              // 16*1056*512*2
#define OFF_Y1  (OFF_Y0 + 16*1056*512*2)

__device__ __forceinline__ void load_lds16(const void* g, void* s) {
    __builtin_amdgcn_global_load_lds(
        (const __attribute__((address_space(1))) void*)g,
        (__attribute__((address_space(3))) void*)s, 16, 0, 0);
}

// ---- weight prep: ws [6][3][512][512] (ci-major in, co inner) -> wt [l][co][t*512+ci] f16
//      w0 [128][512] -> w0t [co][ci] f16
__global__ __launch_bounds__(256)
void wprep(const float* __restrict__ ws, const float* __restrict__ w0,
           _Float16* __restrict__ wt, _Float16* __restrict__ w0t)
{
    __shared__ float t[64][65];
    const int tid = threadIdx.x;
    const int tr = tid >> 6;       // 0..3
    const int tc = tid & 63;
    const int z = blockIdx.z;
    if (z < 18) {
        const int l = z / 3, tp = z % 3;
        const float* src = ws + (size_t)z * 512 * 512;      // [ci][co]
        const int ci0 = blockIdx.y * 64, co0 = blockIdx.x * 64;
        #pragma unroll
        for (int i = 0; i < 16; ++i) { int r = i*4 + tr; t[r][tc] = src[(ci0 + r)*512 + co0 + tc]; }
        __syncthreads();
        _Float16* dst = wt + (size_t)l * 512 * 1536;
        #pragma unroll
        for (int i = 0; i < 16; ++i) { int r = i*4 + tr; dst[(co0 + r)*1536 + tp*512 + ci0 + tc] = (_Float16)t[tc][r]; }
    } else {
        if (blockIdx.y >= 2) return;
        const int ci0 = blockIdx.y * 64, co0 = blockIdx.x * 64;
        #pragma unroll
        for (int i = 0; i < 16; ++i) { int r = i*4 + tr; t[r][tc] = w0[(ci0 + r)*512 + co0 + tc]; }
        __syncthreads();
        #pragma unroll
        for (int i = 0; i < 16; ++i) { int r = i*4 + tr; w0t[(co0 + r)*128 + ci0 + tc] = (_Float16)t[tc][r]; }
    }
}

// ---- zero the 16-row pads of both activation buffers (as u32)
__global__ __launch_bounds__(256)
void zeropad(_Float16* __restrict__ Y0, _Float16* __restrict__ Y1)
{
    const int i = blockIdx.x * 256 + threadIdx.x;       // 262144 total
    const unsigned c2   = i & 255;                      // u32 col (512 f16 / row)
    const unsigned t2   = ((unsigned)i) >> 8;
    const unsigned prow = t2 & 31;
    const unsigned b    = (t2 >> 5) & 15;
    const unsigned buf  = t2 >> 9;
    const unsigned row  = prow < 16 ? prow : (1024 + prow); // [0,16) and [1040,1056)
    unsigned* p = (unsigned*)(buf ? Y1 : Y0);
    p[((size_t)b * 1056 + row) * 256 + c2] = 0u;
}

// ---- bilinear sample + concat -> X0 [16384][128] f16
__global__ __launch_bounds__(256)
void sample_kernel(const float* __restrict__ verts, const float* __restrict__ fm,
                   _Float16* __restrict__ X0)
{
    const int p = blockIdx.x * 4 + (threadIdx.x >> 6);  // 0..16383
    const int lane = threadIdx.x & 63;
    const int b = p >> 10;
    const float vy = verts[p*2], vx = verts[p*2 + 1];
    const float cy = (vy + 1.f) * 127.5f;
    const float cx = (vx + 1.f) * 127.5f;
    const float fy = floorf(cy), fx = floorf(cx);
    const int y0 = (int)fy, x0 = (int)fx;
    const float wy = cy - fy, wx = cx - fx;
    float w00 = (1.f - wy) * (1.f - wx), w01 = (1.f - wy) * wx;
    float w10 = wy * (1.f - wx),         w11 = wy * wx;
    const bool vy0 = (unsigned)y0 < 256u, vy1 = (unsigned)(y0 + 1) < 256u;
    const bool vx0 = (unsigned)x0 < 256u, vx1 = (unsigned)(x0 + 1) < 256u;
    w00 = (vy0 && vx0) ? w00 : 0.f;
    w01 = (vy0 && vx1) ? w01 : 0.f;
    w10 = (vy1 && vx0) ? w10 : 0.f;
    w11 = (vy1 && vx1) ? w11 : 0.f;
    const int yc0 = min(max(y0, 0), 255), yc1 = min(max(y0 + 1, 0), 255);
    const int xc0 = min(max(x0, 0), 255), xc1 = min(max(x0 + 1, 0), 255);
    const float* base = fm + (size_t)b * (256 * 256 * 126);
    const float* p00 = base + (yc0 * 256 + xc0) * 126;
    const float* p01 = base + (yc0 * 256 + xc1) * 126;
    const float* p10 = base + (yc1 * 256 + xc0) * 126;
    const float* p11 = base + (yc1 * 256 + xc1) * 126;
    _Float16* xr = X0 + (size_t)p * 128;
    for (int c = lane; c < 126; c += 64) {
        float a = w00 * p00[c] + w01 * p01[c] + w10 * p10[c] + w11 * p11[c];
        xr[c] = (_Float16)a;
    }
    if (lane < 2) xr[126 + lane] = (_Float16)(lane ? vx : vy);
}

// ---- layer-0 GEMM (K=128), m97 structure, 128x128 tile
template<int KTOT>
__global__ __launch_bounds__(256)
void conv_gemm(const _Float16* __restrict__ A, int a_row_stride, int a_batch_stride,
               const _Float16* __restrict__ WT, const float* __restrict__ bias,
               _Float16* __restrict__ Out, int o_row_stride, int o_batch_stride,
               int dil)
{
    __shared__ _Float16 Ald[BM * BK];
    __shared__ _Float16 Bld[BM * BK];
    const int tid  = threadIdx.x;
    const int wid  = tid >> 6;
    const int lane = tid & 63;
    const int b    = blockIdx.x >> 3;
    const int n0   = (blockIdx.x & 7) * BM;
    const int co0  = blockIdx.y * BM;
    const int wm   = wid >> 1, wn = wid & 1;

    const _Float16* Ab = A + (size_t)b * a_batch_stride + (size_t)n0 * a_row_stride;

    f32x4 acc[4][4] = {};

    const int srow = lane >> 3;
    const int scol = (lane & 7) * 8;

    for (int ks = 0; ks < KTOT / BK; ++ks) {
        int ci0, shift;
        if (KTOT == 128) { ci0 = ks * 64; shift = 0; }
        else             { int t = ks >> 3; ci0 = (ks & 7) * 64; shift = (t - 1) * dil; }
        const _Float16* Arow = Ab + (long)shift * a_row_stride + ci0 + scol;
        const _Float16* Brow = WT + (size_t)co0 * KTOT + ks * 64 + scol;
        #pragma unroll
        for (int i = 0; i < 4; ++i) {
            const int r0 = wid * 32 + i * 8;
            load_lds16(Arow + (size_t)(r0 + srow) * a_row_stride, &Ald[r0 * BK]);
            load_lds16(Brow + (size_t)(r0 + srow) * KTOT,         &Bld[r0 * BK]);
        }
        __syncthreads();
        #pragma unroll
        for (int kf = 0; kf < 2; ++kf) {
            f16x8 af[4], bfr[4];
            #pragma unroll
            for (int f = 0; f < 4; ++f) {
                af[f]  = *(const f16x8*)&Ald[(wm*64 + f*16 + (lane & 15)) * BK + kf*32 + (lane >> 4) * 8];
                bfr[f] = *(const f16x8*)&Bld[(wn*64 + f*16 + (lane & 15)) * BK + kf*32 + (lane >> 4) * 8];
            }
            #pragma unroll
            for (int m = 0; m < 4; ++m)
                #pragma unroll
                for (int n = 0; n < 4; ++n)
                    acc[m][n] = __builtin_amdgcn_mfma_f32_16x16x32_f16(af[m], bfr[n], acc[m][n], 0, 0, 0);
        }
        __syncthreads();
    }

    _Float16* Ob = Out + (size_t)b * o_batch_stride + (size_t)n0 * o_row_stride;
    #pragma unroll
    for (int n = 0; n < 4; ++n) {
        const int co = co0 + wn*64 + n*16 + (lane & 15);
        const float bv = bias[co];
        #pragma unroll
        for (int m = 0; m < 4; ++m) {
            #pragma unroll
            for (int j = 0; j < 4; ++j) {
                const int row = wm*64 + m*16 + (lane >> 4)*4 + j;
                float v = acc[m][n][j] + bv;
                v = fmaxf(v, 0.f);
                Ob[(size_t)row * o_row_stride + co] = (_Float16)v;
            }
        }
    }
}

// ---- mid-layer GEMM (r11): r8 structure (block 256x128, BK=64, 3-deep, 6
// gloads/wave/tile, vmcnt(6), T2 swizzle, single barrier/tile) + SPLIT-K:
// 8 waves = 4 quads (wm,wn of 128x64 tiles) x 2 K-slices (sk = kf).
// Fragment reads/wave/tile: 16 -> 12 (block LDS reads 128 -> 96 KB).
// Epilogue: pairwise acc reduction through LDS (2 rounds x 64 KB).
#define NT8 24
__global__ __launch_bounds__(512, 2)
void conv_gemm8(const _Float16* __restrict__ A, const _Float16* __restrict__ WT,
                const float* __restrict__ bias, _Float16* __restrict__ Out, int dil)
{
    extern __shared__ _Float16 smem[];
    _Float16* Ald = smem;                 // [3][256*64]
    _Float16* Bld = smem + 3 * 256 * 64;  // [3][128*64]

    const int tid  = threadIdx.x;
    const int wid  = tid >> 6;
    const int lane = tid & 63;
    const int q    = wid & 3;             // quad: output sub-tile
    const int sk   = wid >> 2;            // K-slice (kf)
    const int wm   = q >> 1;              // 0..1 : 128-row half
    const int wn   = q & 1;               // 0..1 : 64-col half

    // XCD-aware bijective swizzle (256 blocks, 256%8==0)
    const int orig = blockIdx.x;
    const int swz  = (orig & 7) * 32 + (orig >> 3);
    const int nblk = swz & 3;
    const int mblk = swz >> 2;
    const int b     = mblk >> 2;
    const int n0row = (mblk & 3) * 256;
    const int co0   = nblk * 128;

    const _Float16* Ab = A + (size_t)b * (1056 * 512) + (size_t)n0row * 512;

    // staging: chunk = 64 rows x 64 k (8KB); wave w covers rows 8w..8w+7
    const int srow = lane >> 3;                              // row within wave's 8
    const int scol = (((lane & 7) ^ (lane >> 3)) << 3);      // pre-swizzled global col (f16)

    f32x4 acc[8][4] = {};

    auto stageA = [&](int kt, int c, int ci0, int shift) {
        const int grow = 64 * c + 8 * wid + srow;
        const _Float16* src = Ab + (long)(grow + shift) * 512 + ci0 + scol;
        _Float16* dst = Ald + (kt % 3) * (256 * 64) + (64 * c + 8 * wid) * 64;
        load_lds16(src, dst);
    };
    auto stageB = [&](int kt, int c, int kk) {
        const int grow = 64 * c + 8 * wid + srow;
        const _Float16* src = WT + (size_t)(co0 + grow) * 1536 + kk + scol;
        _Float16* dst = Bld + (kt % 3) * (128 * 64) + (64 * c + 8 * wid) * 64;
        load_lds16(src, dst);
    };
    auto kinfo = [&](int ks, int& ci0, int& shift) {
        const int t = ks >> 3; ci0 = (ks & 7) * 64; shift = (t - 1) * dil;
    };

    // prologue: issue tiles 0 and 1 (6 loads each, fixed order)
    {
        int ci0, sh;
        kinfo(0, ci0, sh);
        stageA(0, 0, ci0, sh); stageA(0, 1, ci0, sh); stageA(0, 2, ci0, sh); stageA(0, 3, ci0, sh);
        stageB(0, 0, 0); stageB(0, 1, 0);
        kinfo(1, ci0, sh);
        stageA(1, 0, ci0, sh); stageA(1, 1, ci0, sh); stageA(1, 2, ci0, sh); stageA(1, 3, ci0, sh);
        stageB(1, 0, 64); stageB(1, 1, 64);
    }

    for (int kt = 0; kt < NT8; ++kt) {
        __builtin_amdgcn_sched_barrier(0);
        if (kt < NT8 - 1) asm volatile("s_waitcnt vmcnt(6)" ::: "memory");
        else              asm volatile("s_waitcnt vmcnt(0)" ::: "memory");
        __builtin_amdgcn_s_barrier();
        __builtin_amdgcn_sched_barrier(0);

        const _Float16* Abuf = Ald + (kt % 3) * (256 * 64);
        const _Float16* Bbuf = Bld + (kt % 3) * (128 * 64);
        const bool do_stage = (kt + 2 < NT8);
        int nci0 = 0, nsh = 0;
        if (do_stage) kinfo(kt + 2, nci0, nsh);

        // 12 fragment reads: only this wave's K-slice (kf = sk)
        f16x8 bfr[4], af[8];
        #pragma unroll
        for (int nf = 0; nf < 4; ++nf) {
            const int row = wn * 64 + nf * 16 + (lane & 15);
            const int slot = (sk * 4 + (lane >> 4)) ^ (row & 7);
            bfr[nf] = *(const f16x8*)&Bbuf[row * 64 + slot * 8];
        }
        #pragma unroll
        for (int mf = 0; mf < 8; ++mf) {
            const int row = wm * 128 + mf * 16 + (lane & 15);
            const int slot = (sk * 4 + (lane >> 4)) ^ (row & 7);
            af[mf] = *(const f16x8*)&Abuf[row * 64 + slot * 8];
        }
        if (do_stage) {
            stageA(kt + 2, 0, nci0, nsh);
            stageA(kt + 2, 1, nci0, nsh);
            stageA(kt + 2, 2, nci0, nsh);
            stageA(kt + 2, 3, nci0, nsh);
            stageB(kt + 2, 0, (kt + 2) * 64);
            stageB(kt + 2, 1, (kt + 2) * 64);
        }
        __builtin_amdgcn_sched_barrier(0);   // stages pinned before MFMA cluster

        __builtin_amdgcn_s_setprio(1);
        #pragma unroll
        for (int mf = 0; mf < 8; ++mf)
            #pragma unroll
            for (int nf = 0; nf < 4; ++nf)
                acc[mf][nf] = __builtin_amdgcn_mfma_f32_16x16x32_f16(
                    af[mf], bfr[nf], acc[mf][nf], 0, 0, 0);
        __builtin_amdgcn_s_setprio(0);
    }

    // ---- split-K reduction (pairs: wid=q (sk=0) <- wid=q+4 (sk=1)) + epilogue.
    // Reuses the (dead) A pipeline LDS region: 4 quads x 4 mf x 4 nf x 64 lanes
    // x 16B = 64 KB per round. All pre-barrier ds_reads are register-consumed.
    float* red = (float*)smem;
    _Float16* Ob = Out + (size_t)b * (1056 * 512) + (size_t)n0row * 512;
    #pragma unroll
    for (int half = 0; half < 2; ++half) {
        __builtin_amdgcn_s_barrier();
        if (sk == 1) {
            #pragma unroll
            for (int mfl = 0; mfl < 4; ++mfl)
                #pragma unroll
                for (int nf = 0; nf < 4; ++nf)
                    *(f32x4*)&red[(((q * 4 + mfl) * 4 + nf) * 64 + lane) * 4] =
                        acc[half * 4 + mfl][nf];
        }
        __builtin_amdgcn_s_barrier();
        if (sk == 0) {
            #pragma unroll
            for (int nf = 0; nf < 4; ++nf) {
                const int co = co0 + wn * 64 + nf * 16 + (lane & 15);
                const float bv = bias[co];
                #pragma unroll
                for (int mfl = 0; mfl < 4; ++mfl) {
                    const int mf = half * 4 + mfl;
                    f32x4 v = *(const f32x4*)&red[(((q * 4 + mfl) * 4 + nf) * 64 + lane) * 4];
                    #pragma unroll
                    for (int j = 0; j < 4; ++j) {
                        const int row = wm * 128 + mf * 16 + (lane >> 4) * 4 + j;
                        float val = acc[mf][nf][j] + v[j] + bv;
                        val = fmaxf(val, 0.f);
                        Ob[(size_t)row * 512 + co] = (_Float16)val;
                    }
                }
            }
        }
    }
}

// ---- final 1x1 conv to 2 channels, fp32 out. One wave per row.
__global__ __launch_bounds__(256)
void final_conv(const _Float16* __restrict__ Y, const float* __restrict__ woff,
                float* __restrict__ out)
{
    const int r = blockIdx.x * 4 + (threadIdx.x >> 6);  // 0..16383
    const int lane = threadIdx.x & 63;
    const int b = r >> 10, n = r & 1023;
    const _Float16* yp = Y + ((size_t)b * 1056 + n) * 512 + lane * 8;
    f16x8 yv = *(const f16x8*)yp;
    const int ci0 = lane * 8;
    float s0 = 0.f, s1 = 0.f;
    #pragma unroll
    for (int e = 0; e < 8; ++e) {
        float y = (float)yv[e];
        s0 += y * woff[(ci0 + e) * 2 + 0];
        s1 += y * woff[(ci0 + e) * 2 + 1];
    }
    #pragma unroll
    for (int off = 32; off; off >>= 1) {
        s0 += __shfl_down(s0, off);
        s1 += __shfl_down(s1, off);
    }
    if (lane == 0) { out[r*2] = s0; out[r*2 + 1] = s1; }
}

extern "C" void kernel_launch(void* const* d_in, const int* in_sizes, int n_in,
                              void* d_out, int out_size, void* d_ws, size_t ws_size,
                              hipStream_t stream)
{
    const float* verts = (const float*)d_in[0];
    const float* fm    = (const float*)d_in[1];
    const float* w0    = (const float*)d_in[2];
    const float* b0    = (const float*)d_in[3];
    const float* ws    = (const float*)d_in[4];
    const float* bs    = (const float*)d_in[5];
    const float* woff  = (const float*)d_in[6];
    float* out = (float*)d_out;

    char* wsp = (char*)d_ws;
    _Float16* W0T = (_Float16*)(wsp + OFF_W0T);
    _Float16* WT  = (_Float16*)(wsp + OFF_WT);
    _Float16* X0  = (_Float16*)(wsp + OFF_X0);
    _Float16* Y0  = (_Float16*)(wsp + OFF_Y0);
    _Float16* Y1  = (_Float16*)(wsp + OFF_Y1);
    _Float16* Y0i = Y0 + 16 * 512;   // interior (row 0 of batch 0)
    _Float16* Y1i = Y1 + 16 * 512;

    hipFuncSetAttribute(reinterpret_cast<const void*>(&conv_gemm8),
                        hipFuncAttributeMaxDynamicSharedMemorySize, 147456);

    wprep<<<dim3(8, 8, 19), 256, 0, stream>>>(ws, w0, WT, W0T);
    zeropad<<<1024, 256, 0, stream>>>(Y0, Y1);
    sample_kernel<<<4096, 256, 0, stream>>>(verts, fm, X0);

    // layer 0: 1x1 conv, K=128 (old structure, small K)
    conv_gemm<128><<<dim3(128, 4), 256, 0, stream>>>(
        X0, 128, 1024 * 128, W0T, b0, Y0i, 512, 1056 * 512, 1);

    // 6 dilated mid layers, K=1536, r11 kernel
    const int DIL[6] = {1, 3, 9, 9, 3, 1};
    _Float16* bufs[2] = {Y0i, Y1i};
    for (int l = 0; l < 6; ++l) {
        conv_gemm8<<<256, 512, 147456, stream>>>(
            bufs[l & 1],
            WT + (size_t)l * 512 * 1536, bs + (size_t)l * 512,
            bufs[(l + 1) & 1], DIL[l]);
    }

    // final projection (reads Y0i after 6 layers)
    final_conv<<<4096, 256, 0, stream>>>(bufs[0], woff, out);
}

// Round 12
// 198.390 us; speedup vs baseline: 2.2268x; 1.0196x over previous
//
#include <hip/hip_runtime.h>

typedef __attribute__((ext_vector_type(4))) float f32x4;
typedef __attribute__((ext_vector_type(8))) _Float16 f16x8;

#define BM 128
#define BK 64

// workspace layout (bytes)
#define OFF_W0T 0                                   // 512*128*2   = 131072
#define OFF_WT  131072                              // 6*512*1536*2 = 9437184
#define OFF_X0  (OFF_WT + 6*512*1536*2)             // 16384*128*2 = 4194304
#define OFF_Y0  (OFF_X0 + 16384*128*2)              // 16*1056*512*2
#define OFF_Y1  (OFF_Y0 + 16*1056*512*2)

__device__ __forceinline__ void load_lds16(const void* g, void* s) {
    __builtin_amdgcn_global_load_lds(
        (const __attribute__((address_space(1))) void*)g,
        (__attribute__((address_space(3))) void*)s, 16, 0, 0);
}

// ---- weight prep: ws [6][3][512][512] (ci-major in, co inner) -> wt [l][co][t*512+ci] f16
//      w0 [128][512] -> w0t [co][ci] f16
__global__ __launch_bounds__(256)
void wprep(const float* __restrict__ ws, const float* __restrict__ w0,
           _Float16* __restrict__ wt, _Float16* __restrict__ w0t)
{
    __shared__ float t[64][65];
    const int tid = threadIdx.x;
    const int tr = tid >> 6;       // 0..3
    const int tc = tid & 63;
    const int z = blockIdx.z;
    if (z < 18) {
        const int l = z / 3, tp = z % 3;
        const float* src = ws + (size_t)z * 512 * 512;      // [ci][co]
        const int ci0 = blockIdx.y * 64, co0 = blockIdx.x * 64;
        #pragma unroll
        for (int i = 0; i < 16; ++i) { int r = i*4 + tr; t[r][tc] = src[(ci0 + r)*512 + co0 + tc]; }
        __syncthreads();
        _Float16* dst = wt + (size_t)l * 512 * 1536;
        #pragma unroll
        for (int i = 0; i < 16; ++i) { int r = i*4 + tr; dst[(co0 + r)*1536 + tp*512 + ci0 + tc] = (_Float16)t[tc][r]; }
    } else {
        if (blockIdx.y >= 2) return;
        const int ci0 = blockIdx.y * 64, co0 = blockIdx.x * 64;
        #pragma unroll
        for (int i = 0; i < 16; ++i) { int r = i*4 + tr; t[r][tc] = w0[(ci0 + r)*512 + co0 + tc]; }
        __syncthreads();
        #pragma unroll
        for (int i = 0; i < 16; ++i) { int r = i*4 + tr; w0t[(co0 + r)*128 + ci0 + tc] = (_Float16)t[tc][r]; }
    }
}

// ---- zero the 16-row pads of both activation buffers (as u32)
__global__ __launch_bounds__(256)
void zeropad(_Float16* __restrict__ Y0, _Float16* __restrict__ Y1)
{
    const int i = blockIdx.x * 256 + threadIdx.x;       // 262144 total
    const unsigned c2   = i & 255;                      // u32 col (512 f16 / row)
    const unsigned t2   = ((unsigned)i) >> 8;
    const unsigned prow = t2 & 31;
    const unsigned b    = (t2 >> 5) & 15;
    const unsigned buf  = t2 >> 9;
    const unsigned row  = prow < 16 ? prow : (1024 + prow); // [0,16) and [1040,1056)
    unsigned* p = (unsigned*)(buf ? Y1 : Y0);
    p[((size_t)b * 1056 + row) * 256 + c2] = 0u;
}

// ---- bilinear sample + concat -> X0 [16384][128] f16
__global__ __launch_bounds__(256)
void sample_kernel(const float* __restrict__ verts, const float* __restrict__ fm,
                   _Float16* __restrict__ X0)
{
    const int p = blockIdx.x * 4 + (threadIdx.x >> 6);  // 0..16383
    const int lane = threadIdx.x & 63;
    const int b = p >> 10;
    const float vy = verts[p*2], vx = verts[p*2 + 1];
    const float cy = (vy + 1.f) * 127.5f;
    const float cx = (vx + 1.f) * 127.5f;
    const float fy = floorf(cy), fx = floorf(cx);
    const int y0 = (int)fy, x0 = (int)fx;
    const float wy = cy - fy, wx = cx - fx;
    float w00 = (1.f - wy) * (1.f - wx), w01 = (1.f - wy) * wx;
    float w10 = wy * (1.f - wx),         w11 = wy * wx;
    const bool vy0 = (unsigned)y0 < 256u, vy1 = (unsigned)(y0 + 1) < 256u;
    const bool vx0 = (unsigned)x0 < 256u, vx1 = (unsigned)(x0 + 1) < 256u;
    w00 = (vy0 && vx0) ? w00 : 0.f;
    w01 = (vy0 && vx1) ? w01 : 0.f;
    w10 = (vy1 && vx0) ? w10 : 0.f;
    w11 = (vy1 && vx1) ? w11 : 0.f;
    const int yc0 = min(max(y0, 0), 255), yc1 = min(max(y0 + 1, 0), 255);
    const int xc0 = min(max(x0, 0), 255), xc1 = min(max(x0 + 1, 0), 255);
    const float* base = fm + (size_t)b * (256 * 256 * 126);
    const float* p00 = base + (yc0 * 256 + xc0) * 126;
    const float* p01 = base + (yc0 * 256 + xc1) * 126;
    const float* p10 = base + (yc1 * 256 + xc0) * 126;
    const float* p11 = base + (yc1 * 256 + xc1) * 126;
    _Float16* xr = X0 + (size_t)p * 128;
    for (int c = lane; c < 126; c += 64) {
        float a = w00 * p00[c] + w01 * p01[c] + w10 * p10[c] + w11 * p11[c];
        xr[c] = (_Float16)a;
    }
    if (lane < 2) xr[126 + lane] = (_Float16)(lane ? vx : vy);
}

// ---- layer-0 GEMM (K=128), m97 structure, 128x128 tile
template<int KTOT>
__global__ __launch_bounds__(256)
void conv_gemm(const _Float16* __restrict__ A, int a_row_stride, int a_batch_stride,
               const _Float16* __restrict__ WT, const float* __restrict__ bias,
               _Float16* __restrict__ Out, int o_row_stride, int o_batch_stride,
               int dil)
{
    __shared__ _Float16 Ald[BM * BK];
    __shared__ _Float16 Bld[BM * BK];
    const int tid  = threadIdx.x;
    const int wid  = tid >> 6;
    const int lane = tid & 63;
    const int b    = blockIdx.x >> 3;
    const int n0   = (blockIdx.x & 7) * BM;
    const int co0  = blockIdx.y * BM;
    const int wm   = wid >> 1, wn = wid & 1;

    const _Float16* Ab = A + (size_t)b * a_batch_stride + (size_t)n0 * a_row_stride;

    f32x4 acc[4][4] = {};

    const int srow = lane >> 3;
    const int scol = (lane & 7) * 8;

    for (int ks = 0; ks < KTOT / BK; ++ks) {
        int ci0, shift;
        if (KTOT == 128) { ci0 = ks * 64; shift = 0; }
        else             { int t = ks >> 3; ci0 = (ks & 7) * 64; shift = (t - 1) * dil; }
        const _Float16* Arow = Ab + (long)shift * a_row_stride + ci0 + scol;
        const _Float16* Brow = WT + (size_t)co0 * KTOT + ks * 64 + scol;
        #pragma unroll
        for (int i = 0; i < 4; ++i) {
            const int r0 = wid * 32 + i * 8;
            load_lds16(Arow + (size_t)(r0 + srow) * a_row_stride, &Ald[r0 * BK]);
            load_lds16(Brow + (size_t)(r0 + srow) * KTOT,         &Bld[r0 * BK]);
        }
        __syncthreads();
        #pragma unroll
        for (int kf = 0; kf < 2; ++kf) {
            f16x8 af[4], bfr[4];
            #pragma unroll
            for (int f = 0; f < 4; ++f) {
                af[f]  = *(const f16x8*)&Ald[(wm*64 + f*16 + (lane & 15)) * BK + kf*32 + (lane >> 4) * 8];
                bfr[f] = *(const f16x8*)&Bld[(wn*64 + f*16 + (lane & 15)) * BK + kf*32 + (lane >> 4) * 8];
            }
            #pragma unroll
            for (int m = 0; m < 4; ++m)
                #pragma unroll
                for (int n = 0; n < 4; ++n)
                    acc[m][n] = __builtin_amdgcn_mfma_f32_16x16x32_f16(af[m], bfr[n], acc[m][n], 0, 0, 0);
        }
        __syncthreads();
    }

    _Float16* Ob = Out + (size_t)b * o_batch_stride + (size_t)n0 * o_row_stride;
    #pragma unroll
    for (int n = 0; n < 4; ++n) {
        const int co = co0 + wn*64 + n*16 + (lane & 15);
        const float bv = bias[co];
        #pragma unroll
        for (int m = 0; m < 4; ++m) {
            #pragma unroll
            for (int j = 0; j < 4; ++j) {
                const int row = wm*64 + m*16 + (lane >> 4)*4 + j;
                float v = acc[m][n][j] + bv;
                v = fmaxf(v, 0.f);
                Ob[(size_t)row * o_row_stride + co] = (_Float16)v;
            }
        }
    }
}

// ---- mid-layer GEMM (r12): r8 geometry (8 waves 4Mx2N, block 256x128, BK=64,
// 3-deep, 6 gloads/wave/tile, vmcnt(6), T2 swizzle, single barrier/tile) with
// sched_group_barrier-forced interleave:
//   {10 dsr} {8 mfma} {2 dsr}{3 vmem} {8 mfma} {2 dsr}{3 vmem} {8 mfma} {2 dsr} {8 mfma}
// MFMA group p consumes frags read one group earlier (in-order lgkmcnt gives
// ~155cyc of MFMA exec to hide ds latency); per-wave MFMA bursts cover the
// sibling wave's LDS read bursts.
#define NT8 24
__global__ __launch_bounds__(512, 2)
void conv_gemm8(const _Float16* __restrict__ A, const _Float16* __restrict__ WT,
                const float* __restrict__ bias, _Float16* __restrict__ Out, int dil)
{
    extern __shared__ _Float16 smem[];
    _Float16* Ald = smem;                 // [3][256*64]
    _Float16* Bld = smem + 3 * 256 * 64;  // [3][128*64]

    const int tid  = threadIdx.x;
    const int wid  = tid >> 6;
    const int lane = tid & 63;
    const int wm   = wid >> 1;            // 0..3 : 64-row band
    const int wn   = wid & 1;             // 0..1 : 64-col half

    // XCD-aware bijective swizzle (256 blocks, 256%8==0)
    const int orig = blockIdx.x;
    const int swz  = (orig & 7) * 32 + (orig >> 3);
    const int nblk = swz & 3;
    const int mblk = swz >> 2;
    const int b     = mblk >> 2;
    const int n0row = (mblk & 3) * 256;
    const int co0   = nblk * 128;

    const _Float16* Ab = A + (size_t)b * (1056 * 512) + (size_t)n0row * 512;

    // staging: chunk = 64 rows x 64 k (8KB); wave w covers rows 8w..8w+7
    const int srow = lane >> 3;                              // row within wave's 8
    const int scol = (((lane & 7) ^ (lane >> 3)) << 3);      // pre-swizzled global col (f16)

    f32x4 acc[4][4] = {};

    auto stageA = [&](int kt, int c, int ci0, int shift) {
        const int grow = 64 * c + 8 * wid + srow;
        const _Float16* src = Ab + (long)(grow + shift) * 512 + ci0 + scol;
        _Float16* dst = Ald + (kt % 3) * (256 * 64) + (64 * c + 8 * wid) * 64;
        load_lds16(src, dst);
    };
    auto stageB = [&](int kt, int c, int kk) {
        const int grow = 64 * c + 8 * wid + srow;
        const _Float16* src = WT + (size_t)(co0 + grow) * 1536 + kk + scol;
        _Float16* dst = Bld + (kt % 3) * (128 * 64) + (64 * c + 8 * wid) * 64;
        load_lds16(src, dst);
    };
    auto kinfo = [&](int ks, int& ci0, int& shift) {
        const int t = ks >> 3; ci0 = (ks & 7) * 64; shift = (t - 1) * dil;
    };

    // prologue: issue tiles 0 and 1 (6 loads each, fixed order)
    {
        int ci0, sh;
        kinfo(0, ci0, sh);
        stageA(0, 0, ci0, sh); stageA(0, 1, ci0, sh); stageA(0, 2, ci0, sh); stageA(0, 3, ci0, sh);
        stageB(0, 0, 0); stageB(0, 1, 0);
        kinfo(1, ci0, sh);
        stageA(1, 0, ci0, sh); stageA(1, 1, ci0, sh); stageA(1, 2, ci0, sh); stageA(1, 3, ci0, sh);
        stageB(1, 0, 64); stageB(1, 1, 64);
    }

    #pragma unroll 1
    for (int kt = 0; kt < NT8; ++kt) {
        // pin all prior work (incl. MFMAs consuming last tile's frags) before the wait
        __builtin_amdgcn_sched_barrier(0);
        if (kt < NT8 - 1) asm volatile("s_waitcnt vmcnt(6)" ::: "memory");
        else              asm volatile("s_waitcnt vmcnt(0)" ::: "memory");
        __builtin_amdgcn_s_barrier();
        __builtin_amdgcn_sched_barrier(0);   // no reads hoisted above the barrier

        const _Float16* Abuf = Ald + (kt % 3) * (256 * 64);
        const _Float16* Bbuf = Bld + (kt % 3) * (128 * 64);
        const bool do_stage = (kt + 2 < NT8);
        int nci0 = 0, nsh = 0;
        if (do_stage) kinfo(kt + 2, nci0, nsh);

        f16x8 bfr[4][2], af[4][2];
        // group 1: 8 bfr + 2 af[0] ds_reads
        #pragma unroll
        for (int nf = 0; nf < 4; ++nf) {
            const int row = wn * 64 + nf * 16 + (lane & 15);
            #pragma unroll
            for (int kf = 0; kf < 2; ++kf) {
                const int slot = (kf * 4 + (lane >> 4)) ^ (row & 7);
                bfr[nf][kf] = *(const f16x8*)&Bbuf[row * 64 + slot * 8];
            }
        }
        {
            const int row = wm * 64 + 0 * 16 + (lane & 15);
            #pragma unroll
            for (int kf = 0; kf < 2; ++kf) {
                const int slot = (kf * 4 + (lane >> 4)) ^ (row & 7);
                af[0][kf] = *(const f16x8*)&Abuf[row * 64 + slot * 8];
            }
        }
        // phase 0 MFMA (mf=0)
        #pragma unroll
        for (int nf = 0; nf < 4; ++nf)
            #pragma unroll
            for (int kf = 0; kf < 2; ++kf)
                acc[0][nf] = __builtin_amdgcn_mfma_f32_16x16x32_f16(af[0][kf], bfr[nf][kf], acc[0][nf], 0, 0, 0);
        // group: af[1] reads + 3 stages
        {
            const int row = wm * 64 + 1 * 16 + (lane & 15);
            #pragma unroll
            for (int kf = 0; kf < 2; ++kf) {
                const int slot = (kf * 4 + (lane >> 4)) ^ (row & 7);
                af[1][kf] = *(const f16x8*)&Abuf[row * 64 + slot * 8];
            }
        }
        if (do_stage) { stageA(kt + 2, 0, nci0, nsh); stageA(kt + 2, 1, nci0, nsh); stageA(kt + 2, 2, nci0, nsh); }
        // phase 1 MFMA (mf=1)
        #pragma unroll
        for (int nf = 0; nf < 4; ++nf)
            #pragma unroll
            for (int kf = 0; kf < 2; ++kf)
                acc[1][nf] = __builtin_amdgcn_mfma_f32_16x16x32_f16(af[1][kf], bfr[nf][kf], acc[1][nf], 0, 0, 0);
        // group: af[2] reads + 3 stages
        {
            const int row = wm * 64 + 2 * 16 + (lane & 15);
            #pragma unroll
            for (int kf = 0; kf < 2; ++kf) {
                const int slot = (kf * 4 + (lane >> 4)) ^ (row & 7);
                af[2][kf] = *(const f16x8*)&Abuf[row * 64 + slot * 8];
            }
        }
        if (do_stage) { stageA(kt + 2, 3, nci0, nsh); stageB(kt + 2, 0, (kt + 2) * 64); stageB(kt + 2, 1, (kt + 2) * 64); }
        // phase 2 MFMA (mf=2)
        #pragma unroll
        for (int nf = 0; nf < 4; ++nf)
            #pragma unroll
            for (int kf = 0; kf < 2; ++kf)
                acc[2][nf] = __builtin_amdgcn_mfma_f32_16x16x32_f16(af[2][kf], bfr[nf][kf], acc[2][nf], 0, 0, 0);
        // group: af[3] reads
        {
            const int row = wm * 64 + 3 * 16 + (lane & 15);
            #pragma unroll
            for (int kf = 0; kf < 2; ++kf) {
                const int slot = (kf * 4 + (lane >> 4)) ^ (row & 7);
                af[3][kf] = *(const f16x8*)&Abuf[row * 64 + slot * 8];
            }
        }
        // phase 3 MFMA (mf=3)
        #pragma unroll
        for (int nf = 0; nf < 4; ++nf)
            #pragma unroll
            for (int kf = 0; kf < 2; ++kf)
                acc[3][nf] = __builtin_amdgcn_mfma_f32_16x16x32_f16(af[3][kf], bfr[nf][kf], acc[3][nf], 0, 0, 0);

        // forced emission order for this region:
        __builtin_amdgcn_sched_group_barrier(0x100, 10, 0);  // bfr(8) + af0(2)
        __builtin_amdgcn_sched_group_barrier(0x008,  8, 0);  // mfma mf0
        __builtin_amdgcn_sched_group_barrier(0x100,  2, 0);  // af1
        __builtin_amdgcn_sched_group_barrier(0x070,  3, 0);  // stages A0-A2
        __builtin_amdgcn_sched_group_barrier(0x008,  8, 0);  // mfma mf1
        __builtin_amdgcn_sched_group_barrier(0x100,  2, 0);  // af2
        __builtin_amdgcn_sched_group_barrier(0x070,  3, 0);  // stages A3,B0,B1
        __builtin_amdgcn_sched_group_barrier(0x008,  8, 0);  // mfma mf2
        __builtin_amdgcn_sched_group_barrier(0x100,  2, 0);  // af3
        __builtin_amdgcn_sched_group_barrier(0x008,  8, 0);  // mfma mf3
    }

    _Float16* Ob = Out + (size_t)b * (1056 * 512) + (size_t)n0row * 512;
    #pragma unroll
    for (int nf = 0; nf < 4; ++nf) {
        const int co = co0 + wn * 64 + nf * 16 + (lane & 15);
        const float bv = bias[co];
        #pragma unroll
        for (int m = 0; m < 4; ++m) {
            #pragma unroll
            for (int j = 0; j < 4; ++j) {
                const int row = wm * 64 + m * 16 + (lane >> 4) * 4 + j;
                float v = acc[m][nf][j] + bv;
                v = fmaxf(v, 0.f);
                Ob[(size_t)row * 512 + co] = (_Float16)v;
            }
        }
    }
}

// ---- final 1x1 conv to 2 channels, fp32 out. One wave per row.
__global__ __launch_bounds__(256)
void final_conv(const _Float16* __restrict__ Y, const float* __restrict__ woff,
                float* __restrict__ out)
{
    const int r = blockIdx.x * 4 + (threadIdx.x >> 6);  // 0..16383
    const int lane = threadIdx.x & 63;
    const int b = r >> 10, n = r & 1023;
    const _Float16* yp = Y + ((size_t)b * 1056 + n) * 512 + lane * 8;
    f16x8 yv = *(const f16x8*)yp;
    const int ci0 = lane * 8;
    float s0 = 0.f, s1 = 0.f;
    #pragma unroll
    for (int e = 0; e < 8; ++e) {
        float y = (float)yv[e];
        s0 += y * woff[(ci0 + e) * 2 + 0];
        s1 += y * woff[(ci0 + e) * 2 + 1];
    }
    #pragma unroll
    for (int off = 32; off; off >>= 1) {
        s0 += __shfl_down(s0, off);
        s1 += __shfl_down(s1, off);
    }
    if (lane == 0) { out[r*2] = s0; out[r*2 + 1] = s1; }
}

extern "C" void kernel_launch(void* const* d_in, const int* in_sizes, int n_in,
                              void* d_out, int out_size, void* d_ws, size_t ws_size,
                              hipStream_t stream)
{
    const float* verts = (const float*)d_in[0];
    const float* fm    = (const float*)d_in[1];
    const float* w0    = (const float*)d_in[2];
    const float* b0    = (const float*)d_in[3];
    const float* ws    = (const float*)d_in[4];
    const float* bs    = (const float*)d_in[5];
    const float* woff  = (const float*)d_in[6];
    float* out = (float*)d_out;

    char* wsp = (char*)d_ws;
    _Float16* W0T = (_Float16*)(wsp + OFF_W0T);
    _Float16* WT  = (_Float16*)(wsp + OFF_WT);
    _Float16* X0  = (_Float16*)(wsp + OFF_X0);
    _Float16* Y0  = (_Float16*)(wsp + OFF_Y0);
    _Float16* Y1  = (_Float16*)(wsp + OFF_Y1);
    _Float16* Y0i = Y0 + 16 * 512;   // interior (row 0 of batch 0)
    _Float16* Y1i = Y1 + 16 * 512;

    hipFuncSetAttribute(reinterpret_cast<const void*>(&conv_gemm8),
                        hipFuncAttributeMaxDynamicSharedMemorySize, 147456);

    wprep<<<dim3(8, 8, 19), 256, 0, stream>>>(ws, w0, WT, W0T);
    zeropad<<<1024, 256, 0, stream>>>(Y0, Y1);
    sample_kernel<<<4096, 256, 0, stream>>>(verts, fm, X0);

    // layer 0: 1x1 conv, K=128 (old structure, small K)
    conv_gemm<128><<<dim3(128, 4), 256, 0, stream>>>(
        X0, 128, 1024 * 128, W0T, b0, Y0i, 512, 1056 * 512, 1);

    // 6 dilated mid layers, K=1536, r12 kernel
    const int DIL[6] = {1, 3, 9, 9, 3, 1};
    _Float16* bufs[2] = {Y0i, Y1i};
    for (int l = 0; l < 6; ++l) {
        conv_gemm8<<<256, 512, 147456, stream>>>(
            bufs[l & 1],
            WT + (size_t)l * 512 * 1536, bs + (size_t)l * 512,
            bufs[(l + 1) & 1], DIL[l]);
    }

    // final projection (reads Y0i after 6 layers)
    final_conv<<<4096, 256, 0, stream>>>(bufs[0], woff, out);
}

// Round 13
// 179.295 us; speedup vs baseline: 2.4639x; 1.1065x over previous
//
#include <hip/hip_runtime.h>

typedef __attribute__((ext_vector_type(4))) float f32x4;
typedef __attribute__((ext_vector_type(8))) _Float16 f16x8;

#define BM 128
#define BK 64

// workspace layout (bytes)
#define OFF_W0T 0                                   // 512*128*2   = 131072
#define OFF_WT  131072                              // 6*512*1536*2 = 9437184
#define OFF_X0  (OFF_WT + 6*512*1536*2)             // 16384*128*2 = 4194304
#define OFF_Y0  (OFF_X0 + 16384*128*2)              // 16*1056*512*2
#define OFF_Y1  (OFF_Y0 + 16*1056*512*2)

__device__ __forceinline__ void load_lds16(const void* g, void* s) {
    __builtin_amdgcn_global_load_lds(
        (const __attribute__((address_space(1))) void*)g,
        (__attribute__((address_space(3))) void*)s, 16, 0, 0);
}

template<int N> struct IC { static constexpr int v = N; };

// ---- weight prep: ws [6][3][512][512] (ci-major in, co inner) -> wt [l][co][t*512+ci] f16
//      w0 [128][512] -> w0t [co][ci] f16
__global__ __launch_bounds__(256)
void wprep(const float* __restrict__ ws, const float* __restrict__ w0,
           _Float16* __restrict__ wt, _Float16* __restrict__ w0t)
{
    __shared__ float t[64][65];
    const int tid = threadIdx.x;
    const int tr = tid >> 6;       // 0..3
    const int tc = tid & 63;
    const int z = blockIdx.z;
    if (z < 18) {
        const int l = z / 3, tp = z % 3;
        const float* src = ws + (size_t)z * 512 * 512;      // [ci][co]
        const int ci0 = blockIdx.y * 64, co0 = blockIdx.x * 64;
        #pragma unroll
        for (int i = 0; i < 16; ++i) { int r = i*4 + tr; t[r][tc] = src[(ci0 + r)*512 + co0 + tc]; }
        __syncthreads();
        _Float16* dst = wt + (size_t)l * 512 * 1536;
        #pragma unroll
        for (int i = 0; i < 16; ++i) { int r = i*4 + tr; dst[(co0 + r)*1536 + tp*512 + ci0 + tc] = (_Float16)t[tc][r]; }
    } else {
        if (blockIdx.y >= 2) return;
        const int ci0 = blockIdx.y * 64, co0 = blockIdx.x * 64;
        #pragma unroll
        for (int i = 0; i < 16; ++i) { int r = i*4 + tr; t[r][tc] = w0[(ci0 + r)*512 + co0 + tc]; }
        __syncthreads();
        #pragma unroll
        for (int i = 0; i < 16; ++i) { int r = i*4 + tr; w0t[(co0 + r)*128 + ci0 + tc] = (_Float16)t[tc][r]; }
    }
}

// ---- zero the 16-row pads of both activation buffers (as u32)
__global__ __launch_bounds__(256)
void zeropad(_Float16* __restrict__ Y0, _Float16* __restrict__ Y1)
{
    const int i = blockIdx.x * 256 + threadIdx.x;       // 262144 total
    const unsigned c2   = i & 255;                      // u32 col (512 f16 / row)
    const unsigned t2   = ((unsigned)i) >> 8;
    const unsigned prow = t2 & 31;
    const unsigned b    = (t2 >> 5) & 15;
    const unsigned buf  = t2 >> 9;
    const unsigned row  = prow < 16 ? prow : (1024 + prow); // [0,16) and [1040,1056)
    unsigned* p = (unsigned*)(buf ? Y1 : Y0);
    p[((size_t)b * 1056 + row) * 256 + c2] = 0u;
}

// ---- bilinear sample + concat -> X0 [16384][128] f16
__global__ __launch_bounds__(256)
void sample_kernel(const float* __restrict__ verts, const float* __restrict__ fm,
                   _Float16* __restrict__ X0)
{
    const int p = blockIdx.x * 4 + (threadIdx.x >> 6);  // 0..16383
    const int lane = threadIdx.x & 63;
    const int b = p >> 10;
    const float vy = verts[p*2], vx = verts[p*2 + 1];
    const float cy = (vy + 1.f) * 127.5f;
    const float cx = (vx + 1.f) * 127.5f;
    const float fy = floorf(cy), fx = floorf(cx);
    const int y0 = (int)fy, x0 = (int)fx;
    const float wy = cy - fy, wx = cx - fx;
    float w00 = (1.f - wy) * (1.f - wx), w01 = (1.f - wy) * wx;
    float w10 = wy * (1.f - wx),         w11 = wy * wx;
    const bool vy0 = (unsigned)y0 < 256u, vy1 = (unsigned)(y0 + 1) < 256u;
    const bool vx0 = (unsigned)x0 < 256u, vx1 = (unsigned)(x0 + 1) < 256u;
    w00 = (vy0 && vx0) ? w00 : 0.f;
    w01 = (vy0 && vx1) ? w01 : 0.f;
    w10 = (vy1 && vx0) ? w10 : 0.f;
    w11 = (vy1 && vx1) ? w11 : 0.f;
    const int yc0 = min(max(y0, 0), 255), yc1 = min(max(y0 + 1, 0), 255);
    const int xc0 = min(max(x0, 0), 255), xc1 = min(max(x0 + 1, 0), 255);
    const float* base = fm + (size_t)b * (256 * 256 * 126);
    const float* p00 = base + (yc0 * 256 + xc0) * 126;
    const float* p01 = base + (yc0 * 256 + xc1) * 126;
    const float* p10 = base + (yc1 * 256 + xc0) * 126;
    const float* p11 = base + (yc1 * 256 + xc1) * 126;
    _Float16* xr = X0 + (size_t)p * 128;
    for (int c = lane; c < 126; c += 64) {
        float a = w00 * p00[c] + w01 * p01[c] + w10 * p10[c] + w11 * p11[c];
        xr[c] = (_Float16)a;
    }
    if (lane < 2) xr[126 + lane] = (_Float16)(lane ? vx : vy);
}

// ---- layer-0 GEMM (K=128), m97 structure, 128x128 tile
template<int KTOT>
__global__ __launch_bounds__(256)
void conv_gemm(const _Float16* __restrict__ A, int a_row_stride, int a_batch_stride,
               const _Float16* __restrict__ WT, const float* __restrict__ bias,
               _Float16* __restrict__ Out, int o_row_stride, int o_batch_stride,
               int dil)
{
    __shared__ _Float16 Ald[BM * BK];
    __shared__ _Float16 Bld[BM * BK];
    const int tid  = threadIdx.x;
    const int wid  = tid >> 6;
    const int lane = tid & 63;
    const int b    = blockIdx.x >> 3;
    const int n0   = (blockIdx.x & 7) * BM;
    const int co0  = blockIdx.y * BM;
    const int wm   = wid >> 1, wn = wid & 1;

    const _Float16* Ab = A + (size_t)b * a_batch_stride + (size_t)n0 * a_row_stride;

    f32x4 acc[4][4] = {};

    const int srow = lane >> 3;
    const int scol = (lane & 7) * 8;

    for (int ks = 0; ks < KTOT / BK; ++ks) {
        int ci0, shift;
        if (KTOT == 128) { ci0 = ks * 64; shift = 0; }
        else             { int t = ks >> 3; ci0 = (ks & 7) * 64; shift = (t - 1) * dil; }
        const _Float16* Arow = Ab + (long)shift * a_row_stride + ci0 + scol;
        const _Float16* Brow = WT + (size_t)co0 * KTOT + ks * 64 + scol;
        #pragma unroll
        for (int i = 0; i < 4; ++i) {
            const int r0 = wid * 32 + i * 8;
            load_lds16(Arow + (size_t)(r0 + srow) * a_row_stride, &Ald[r0 * BK]);
            load_lds16(Brow + (size_t)(r0 + srow) * KTOT,         &Bld[r0 * BK]);
        }
        __syncthreads();
        #pragma unroll
        for (int kf = 0; kf < 2; ++kf) {
            f16x8 af[4], bfr[4];
            #pragma unroll
            for (int f = 0; f < 4; ++f) {
                af[f]  = *(const f16x8*)&Ald[(wm*64 + f*16 + (lane & 15)) * BK + kf*32 + (lane >> 4) * 8];
                bfr[f] = *(const f16x8*)&Bld[(wn*64 + f*16 + (lane & 15)) * BK + kf*32 + (lane >> 4) * 8];
            }
            #pragma unroll
            for (int m = 0; m < 4; ++m)
                #pragma unroll
                for (int n = 0; n < 4; ++n)
                    acc[m][n] = __builtin_amdgcn_mfma_f32_16x16x32_f16(af[m], bfr[n], acc[m][n], 0, 0, 0);
        }
        __syncthreads();
    }

    _Float16* Ob = Out + (size_t)b * o_batch_stride + (size_t)n0 * o_row_stride;
    #pragma unroll
    for (int n = 0; n < 4; ++n) {
        const int co = co0 + wn*64 + n*16 + (lane & 15);
        const float bv = bias[co];
        #pragma unroll
        for (int m = 0; m < 4; ++m) {
            #pragma unroll
            for (int j = 0; j < 4; ++j) {
                const int row = wm*64 + m*16 + (lane >> 4)*4 + j;
                float v = acc[m][n][j] + bv;
                v = fmaxf(v, 0.f);
                Ob[(size_t)row * o_row_stride + co] = (_Float16)v;
            }
        }
    }
}

// ---- mid-layer GEMM (r13): r12 base + A-halo reuse. K-loop reordered to
// ci-chunk-outer (8 chunks of 64 ci), tap-inner (3). A staged ONCE per chunk
// as a 320-row x 64-ci slab (40KB) covering all tap shifts (+-9 within 32-row
// margin); tap bodies read with row offset. A double-buffered (2x40KB) + B
// 3-deep (3x16KB) = 128KB LDS. Per-wave VMEM order: [A5 at tap0, B2, B2...]
// -> waits: tap0 vmcnt(2), tap1 vmcnt(7), tap2 vmcnt(2); chunk-7 peeled
// (2/2/0). Stage-writes 96->40KB per 3 tiles; A HBM fetch 3x -> 1x.
#define ACH_ELEMS (320 * 64)
#define BBUF_ELEMS (128 * 64)
__global__ __launch_bounds__(512, 2)
void conv_gemm8(const _Float16* __restrict__ A, const _Float16* __restrict__ WT,
                const float* __restrict__ bias, _Float16* __restrict__ Out, int dil)
{
    extern __shared__ _Float16 smem[];
    _Float16* Ald = smem;                      // [2][320*64]
    _Float16* Bld = smem + 2 * ACH_ELEMS;      // [3][128*64]

    const int tid  = threadIdx.x;
    const int wid  = tid >> 6;
    const int lane = tid & 63;
    const int wm   = wid >> 1;            // 0..3 : 64-row band
    const int wn   = wid & 1;             // 0..1 : 64-col half

    // XCD-aware bijective swizzle (256 blocks, 256%8==0)
    const int orig = blockIdx.x;
    const int swz  = (orig & 7) * 32 + (orig >> 3);
    const int nblk = swz & 3;
    const int mblk = swz >> 2;
    const int b     = mblk >> 2;
    const int n0row = (mblk & 3) * 256;
    const int co0   = nblk * 128;

    const _Float16* Ab = A + (size_t)b * (1056 * 512) + (size_t)n0row * 512;

    const int srow = lane >> 3;                              // row within 8-row group
    const int scol = (((lane & 7) ^ (lane >> 3)) << 3);      // pre-swizzled global col (f16)

    f32x4 acc[4][4] = {};

    // one A-chunk staging load (i = 0..4): 8-row group (wid + 8i), rows rel. n0row-32
    auto stageA1 = [&](int cn, int i) {
        const int rb = 8 * (wid + 8 * i);                    // 0..312
        const _Float16* src = Ab + (long)(rb + srow - 32) * 512 + cn * 64 + scol;
        load_lds16(src, Ald + (cn & 1) * ACH_ELEMS + rb * 64);
    };
    // one B staging load (cc = 0,1): K-tile (c2, t2) -> buffer t2
    auto stageB1 = [&](int c2, int t2, int cc) {
        const int grow = 64 * cc + 8 * wid + srow;
        const _Float16* src = WT + (size_t)(co0 + grow) * 1536 + (t2 * 512 + c2 * 64) + scol;
        load_lds16(src, Bld + t2 * BBUF_ELEMS + (64 * cc + 8 * wid) * 64);
    };

    // prologue: A(0) x5, B(0,0) x2, B(0,1) x2  -> outstanding [A5,B2,B2]
    stageA1(0, 0); stageA1(0, 1); stageA1(0, 2); stageA1(0, 3); stageA1(0, 4);
    stageB1(0, 0, 0); stageB1(0, 0, 1);
    stageB1(0, 1, 0); stageB1(0, 1, 1);

    auto body = [&](auto TAPc, auto DOAc, int c) {
        constexpr int TAP = decltype(TAPc)::v;
        constexpr int DOA = decltype(DOAc)::v;     // 1 = main chunks (c<7)

        __builtin_amdgcn_sched_barrier(0);
        if constexpr (TAP == 1 && DOA)       asm volatile("s_waitcnt vmcnt(7)" ::: "memory");
        else if constexpr (TAP == 2 && !DOA) asm volatile("s_waitcnt vmcnt(0)" ::: "memory");
        else                                 asm volatile("s_waitcnt vmcnt(2)" ::: "memory");
        __builtin_amdgcn_s_barrier();
        __builtin_amdgcn_sched_barrier(0);

        const _Float16* Abuf = Ald + (c & 1) * ACH_ELEMS;
        const _Float16* Bbuf = Bld + TAP * BBUF_ELEMS;
        const int shift = (TAP - 1) * dil;
        const int rbase = 32 + wm * 64 + (lane & 15) + shift;  // 16|mf*16 keeps key const
        const int akey  = rbase & 7;
        const int bkey  = lane & 7;

        f16x8 bfr[4][2], af[4][2];
        // group: 8 bfr + 2 af[0]
        #pragma unroll
        for (int nf = 0; nf < 4; ++nf) {
            const int row = wn * 64 + nf * 16 + (lane & 15);
            #pragma unroll
            for (int kf = 0; kf < 2; ++kf) {
                const int slot = (kf * 4 + (lane >> 4)) ^ bkey;
                bfr[nf][kf] = *(const f16x8*)&Bbuf[row * 64 + slot * 8];
            }
        }
        #pragma unroll
        for (int kf = 0; kf < 2; ++kf) {
            const int slot = (kf * 4 + (lane >> 4)) ^ akey;
            af[0][kf] = *(const f16x8*)&Abuf[rbase * 64 + slot * 8];
        }
        // mfma mf0
        #pragma unroll
        for (int nf = 0; nf < 4; ++nf)
            #pragma unroll
            for (int kf = 0; kf < 2; ++kf)
                acc[0][nf] = __builtin_amdgcn_mfma_f32_16x16x32_f16(af[0][kf], bfr[nf][kf], acc[0][nf], 0, 0, 0);
        // af1 + stage part1
        #pragma unroll
        for (int kf = 0; kf < 2; ++kf) {
            const int slot = (kf * 4 + (lane >> 4)) ^ akey;
            af[1][kf] = *(const f16x8*)&Abuf[(rbase + 16) * 64 + slot * 8];
        }
        if constexpr (TAP == 0 && DOA) {
            stageA1(c + 1, 0); stageA1(c + 1, 1); stageA1(c + 1, 2); stageA1(c + 1, 3);
        } else if constexpr (TAP == 0) {
            stageB1(7, 2, 0);                    // peeled c=7 tap0: B(23) part1
        } else if constexpr (DOA) {
            if constexpr (TAP == 1) stageB1(c + 1, 0, 0);
            else                    stageB1(c + 1, 1, 0);
        }
        // mfma mf1
        #pragma unroll
        for (int nf = 0; nf < 4; ++nf)
            #pragma unroll
            for (int kf = 0; kf < 2; ++kf)
                acc[1][nf] = __builtin_amdgcn_mfma_f32_16x16x32_f16(af[1][kf], bfr[nf][kf], acc[1][nf], 0, 0, 0);
        // af2 + stage part2
        #pragma unroll
        for (int kf = 0; kf < 2; ++kf) {
            const int slot = (kf * 4 + (lane >> 4)) ^ akey;
            af[2][kf] = *(const f16x8*)&Abuf[(rbase + 32) * 64 + slot * 8];
        }
        if constexpr (TAP == 0 && DOA) {
            stageA1(c + 1, 4);
            stageB1(c, 2, 0); stageB1(c, 2, 1);  // B(3c+2)
        } else if constexpr (TAP == 0) {
            stageB1(7, 2, 1);                    // peeled: B(23) part2
        } else if constexpr (DOA) {
            if constexpr (TAP == 1) stageB1(c + 1, 0, 1);
            else                    stageB1(c + 1, 1, 1);
        }
        // mfma mf2
        #pragma unroll
        for (int nf = 0; nf < 4; ++nf)
            #pragma unroll
            for (int kf = 0; kf < 2; ++kf)
                acc[2][nf] = __builtin_amdgcn_mfma_f32_16x16x32_f16(af[2][kf], bfr[nf][kf], acc[2][nf], 0, 0, 0);
        // af3
        #pragma unroll
        for (int kf = 0; kf < 2; ++kf) {
            const int slot = (kf * 4 + (lane >> 4)) ^ akey;
            af[3][kf] = *(const f16x8*)&Abuf[(rbase + 48) * 64 + slot * 8];
        }
        // mfma mf3
        #pragma unroll
        for (int nf = 0; nf < 4; ++nf)
            #pragma unroll
            for (int kf = 0; kf < 2; ++kf)
                acc[3][nf] = __builtin_amdgcn_mfma_f32_16x16x32_f16(af[3][kf], bfr[nf][kf], acc[3][nf], 0, 0, 0);

        if constexpr (DOA) {
            if constexpr (TAP == 0) {
                __builtin_amdgcn_sched_group_barrier(0x100, 10, 0);
                __builtin_amdgcn_sched_group_barrier(0x008,  8, 0);
                __builtin_amdgcn_sched_group_barrier(0x100,  2, 0);
                __builtin_amdgcn_sched_group_barrier(0x070,  4, 0);
                __builtin_amdgcn_sched_group_barrier(0x008,  8, 0);
                __builtin_amdgcn_sched_group_barrier(0x100,  2, 0);
                __builtin_amdgcn_sched_group_barrier(0x070,  3, 0);
                __builtin_amdgcn_sched_group_barrier(0x008,  8, 0);
                __builtin_amdgcn_sched_group_barrier(0x100,  2, 0);
                __builtin_amdgcn_sched_group_barrier(0x008,  8, 0);
            } else {
                __builtin_amdgcn_sched_group_barrier(0x100, 10, 0);
                __builtin_amdgcn_sched_group_barrier(0x008,  8, 0);
                __builtin_amdgcn_sched_group_barrier(0x100,  2, 0);
                __builtin_amdgcn_sched_group_barrier(0x070,  1, 0);
                __builtin_amdgcn_sched_group_barrier(0x008,  8, 0);
                __builtin_amdgcn_sched_group_barrier(0x100,  2, 0);
                __builtin_amdgcn_sched_group_barrier(0x070,  1, 0);
                __builtin_amdgcn_sched_group_barrier(0x008,  8, 0);
                __builtin_amdgcn_sched_group_barrier(0x100,  2, 0);
                __builtin_amdgcn_sched_group_barrier(0x008,  8, 0);
            }
        }
    };

    #pragma unroll 1
    for (int c = 0; c < 7; ++c) {
        body(IC<0>{}, IC<1>{}, c);
        body(IC<1>{}, IC<1>{}, c);
        body(IC<2>{}, IC<1>{}, c);
    }
    body(IC<0>{}, IC<0>{}, 7);
    body(IC<1>{}, IC<0>{}, 7);
    body(IC<2>{}, IC<0>{}, 7);

    _Float16* Ob = Out + (size_t)b * (1056 * 512) + (size_t)n0row * 512;
    #pragma unroll
    for (int nf = 0; nf < 4; ++nf) {
        const int co = co0 + wn * 64 + nf * 16 + (lane & 15);
        const float bv = bias[co];
        #pragma unroll
        for (int m = 0; m < 4; ++m) {
            #pragma unroll
            for (int j = 0; j < 4; ++j) {
                const int row = wm * 64 + m * 16 + (lane >> 4) * 4 + j;
                float v = acc[m][nf][j] + bv;
                v = fmaxf(v, 0.f);
                Ob[(size_t)row * 512 + co] = (_Float16)v;
            }
        }
    }
}

// ---- final 1x1 conv to 2 channels, fp32 out. One wave per row.
__global__ __launch_bounds__(256)
void final_conv(const _Float16* __restrict__ Y, const float* __restrict__ woff,
                float* __restrict__ out)
{
    const int r = blockIdx.x * 4 + (threadIdx.x >> 6);  // 0..16383
    const int lane = threadIdx.x & 63;
    const int b = r >> 10, n = r & 1023;
    const _Float16* yp = Y + ((size_t)b * 1056 + n) * 512 + lane * 8;
    f16x8 yv = *(const f16x8*)yp;
    const int ci0 = lane * 8;
    float s0 = 0.f, s1 = 0.f;
    #pragma unroll
    for (int e = 0; e < 8; ++e) {
        float y = (float)yv[e];
        s0 += y * woff[(ci0 + e) * 2 + 0];
        s1 += y * woff[(ci0 + e) * 2 + 1];
    }
    #pragma unroll
    for (int off = 32; off; off >>= 1) {
        s0 += __shfl_down(s0, off);
        s1 += __shfl_down(s1, off);
    }
    if (lane == 0) { out[r*2] = s0; out[r*2 + 1] = s1; }
}

extern "C" void kernel_launch(void* const* d_in, const int* in_sizes, int n_in,
                              void* d_out, int out_size, void* d_ws, size_t ws_size,
                              hipStream_t stream)
{
    const float* verts = (const float*)d_in[0];
    const float* fm    = (const float*)d_in[1];
    const float* w0    = (const float*)d_in[2];
    const float* b0    = (const float*)d_in[3];
    const float* ws    = (const float*)d_in[4];
    const float* bs    = (const float*)d_in[5];
    const float* woff  = (const float*)d_in[6];
    float* out = (float*)d_out;

    char* wsp = (char*)d_ws;
    _Float16* W0T = (_Float16*)(wsp + OFF_W0T);
    _Float16* WT  = (_Float16*)(wsp + OFF_WT);
    _Float16* X0  = (_Float16*)(wsp + OFF_X0);
    _Float16* Y0  = (_Float16*)(wsp + OFF_Y0);
    _Float16* Y1  = (_Float16*)(wsp + OFF_Y1);
    _Float16* Y0i = Y0 + 16 * 512;   // interior (row 0 of batch 0)
    _Float16* Y1i = Y1 + 16 * 512;

    hipFuncSetAttribute(reinterpret_cast<const void*>(&conv_gemm8),
                        hipFuncAttributeMaxDynamicSharedMemorySize, 131072);

    wprep<<<dim3(8, 8, 19), 256, 0, stream>>>(ws, w0, WT, W0T);
    zeropad<<<1024, 256, 0, stream>>>(Y0, Y1);
    sample_kernel<<<4096, 256, 0, stream>>>(verts, fm, X0);

    // layer 0: 1x1 conv, K=128 (old structure, small K)
    conv_gemm<128><<<dim3(128, 4), 256, 0, stream>>>(
        X0, 128, 1024 * 128, W0T, b0, Y0i, 512, 1056 * 512, 1);

    // 6 dilated mid layers, K=1536, r13 kernel
    const int DIL[6] = {1, 3, 9, 9, 3, 1};
    _Float16* bufs[2] = {Y0i, Y1i};
    for (int l = 0; l < 6; ++l) {
        conv_gemm8<<<256, 512, 131072, stream>>>(
            bufs[l & 1],
            WT + (size_t)l * 512 * 1536, bs + (size_t)l * 512,
            bufs[(l + 1) & 1], DIL[l]);
    }

    // final projection (reads Y0i after 6 layers)
    final_conv<<<4096, 256, 0, stream>>>(bufs[0], woff, out);
}

// Round 14
// 176.086 us; speedup vs baseline: 2.5088x; 1.0182x over previous
//
#include <hip/hip_runtime.h>

typedef __attribute__((ext_vector_type(4))) float f32x4;
typedef __attribute__((ext_vector_type(8))) _Float16 f16x8;

#define BM 128
#define BK 64

// workspace layout (bytes)
#define OFF_W0T 0                                   // 512*128*2   = 131072
#define OFF_WT  131072                              // 6*512*1536*2 = 9437184
#define OFF_X0  (OFF_WT + 6*512*1536*2)             // 16384*128*2 = 4194304
#define OFF_Y0  (OFF_X0 + 16384*128*2)              // 16*1056*512*2
#define OFF_Y1  (OFF_Y0 + 16*1056*512*2)

__device__ __forceinline__ void load_lds16(const void* g, void* s) {
    __builtin_amdgcn_global_load_lds(
        (const __attribute__((address_space(1))) void*)g,
        (__attribute__((address_space(3))) void*)s, 16, 0, 0);
}

template<int N> struct IC { static constexpr int v = N; };

// ---- weight prep: ws [6][3][512][512] (ci-major in, co inner) -> wt [l][co][t*512+ci] f16
//      w0 [128][512] -> w0t [co][ci] f16
__global__ __launch_bounds__(256)
void wprep(const float* __restrict__ ws, const float* __restrict__ w0,
           _Float16* __restrict__ wt, _Float16* __restrict__ w0t)
{
    __shared__ float t[64][65];
    const int tid = threadIdx.x;
    const int tr = tid >> 6;       // 0..3
    const int tc = tid & 63;
    const int z = blockIdx.z;
    if (z < 18) {
        const int l = z / 3, tp = z % 3;
        const float* src = ws + (size_t)z * 512 * 512;      // [ci][co]
        const int ci0 = blockIdx.y * 64, co0 = blockIdx.x * 64;
        #pragma unroll
        for (int i = 0; i < 16; ++i) { int r = i*4 + tr; t[r][tc] = src[(ci0 + r)*512 + co0 + tc]; }
        __syncthreads();
        _Float16* dst = wt + (size_t)l * 512 * 1536;
        #pragma unroll
        for (int i = 0; i < 16; ++i) { int r = i*4 + tr; dst[(co0 + r)*1536 + tp*512 + ci0 + tc] = (_Float16)t[tc][r]; }
    } else {
        if (blockIdx.y >= 2) return;
        const int ci0 = blockIdx.y * 64, co0 = blockIdx.x * 64;
        #pragma unroll
        for (int i = 0; i < 16; ++i) { int r = i*4 + tr; t[r][tc] = w0[(ci0 + r)*512 + co0 + tc]; }
        __syncthreads();
        #pragma unroll
        for (int i = 0; i < 16; ++i) { int r = i*4 + tr; w0t[(co0 + r)*128 + ci0 + tc] = (_Float16)t[tc][r]; }
    }
}

// ---- fused: zero the 16-row pads of Y0/Y1 (blocks 0..1023) + bilinear sample
//      -> X0 [16384][128] f16 (blocks 1024..5119)
__global__ __launch_bounds__(256)
void sample_pad_kernel(const float* __restrict__ verts, const float* __restrict__ fm,
                       _Float16* __restrict__ X0, _Float16* __restrict__ Y0,
                       _Float16* __restrict__ Y1)
{
    if (blockIdx.x < 1024) {
        const int i = blockIdx.x * 256 + threadIdx.x;       // 262144 total
        const unsigned c2   = i & 255;                      // u32 col (512 f16 / row)
        const unsigned t2   = ((unsigned)i) >> 8;
        const unsigned prow = t2 & 31;
        const unsigned b    = (t2 >> 5) & 15;
        const unsigned buf  = t2 >> 9;
        const unsigned row  = prow < 16 ? prow : (1024 + prow); // [0,16) and [1040,1056)
        unsigned* p = (unsigned*)(buf ? Y1 : Y0);
        p[((size_t)b * 1056 + row) * 256 + c2] = 0u;
        return;
    }
    const int p = (blockIdx.x - 1024) * 4 + (threadIdx.x >> 6);  // 0..16383
    const int lane = threadIdx.x & 63;
    const int b = p >> 10;
    const float vy = verts[p*2], vx = verts[p*2 + 1];
    const float cy = (vy + 1.f) * 127.5f;
    const float cx = (vx + 1.f) * 127.5f;
    const float fy = floorf(cy), fx = floorf(cx);
    const int y0 = (int)fy, x0 = (int)fx;
    const float wy = cy - fy, wx = cx - fx;
    float w00 = (1.f - wy) * (1.f - wx), w01 = (1.f - wy) * wx;
    float w10 = wy * (1.f - wx),         w11 = wy * wx;
    const bool vy0 = (unsigned)y0 < 256u, vy1 = (unsigned)(y0 + 1) < 256u;
    const bool vx0 = (unsigned)x0 < 256u, vx1 = (unsigned)(x0 + 1) < 256u;
    w00 = (vy0 && vx0) ? w00 : 0.f;
    w01 = (vy0 && vx1) ? w01 : 0.f;
    w10 = (vy1 && vx0) ? w10 : 0.f;
    w11 = (vy1 && vx1) ? w11 : 0.f;
    const int yc0 = min(max(y0, 0), 255), yc1 = min(max(y0 + 1, 0), 255);
    const int xc0 = min(max(x0, 0), 255), xc1 = min(max(x0 + 1, 0), 255);
    const float* base = fm + (size_t)b * (256 * 256 * 126);
    const float* p00 = base + (yc0 * 256 + xc0) * 126;
    const float* p01 = base + (yc0 * 256 + xc1) * 126;
    const float* p10 = base + (yc1 * 256 + xc0) * 126;
    const float* p11 = base + (yc1 * 256 + xc1) * 126;
    _Float16* xr = X0 + (size_t)p * 128;
    for (int c = lane; c < 126; c += 64) {
        float a = w00 * p00[c] + w01 * p01[c] + w10 * p10[c] + w11 * p11[c];
        xr[c] = (_Float16)a;
    }
    if (lane < 2) xr[126 + lane] = (_Float16)(lane ? vx : vy);
}

// ---- layer-0 GEMM (r14): K=128, both K-tiles prefetched, counted vmcnt,
// one barrier per K-tile, T2 swizzle. Block 128x128, 4 waves 2Mx2N (64x64
// wave-tiles), 64KB LDS, 2 blocks/CU.
__global__ __launch_bounds__(256, 2)
void conv_gemm0(const _Float16* __restrict__ A, const _Float16* __restrict__ WT,
                const float* __restrict__ bias, _Float16* __restrict__ Out)
{
    __shared__ _Float16 Ald[2][128 * 64];
    __shared__ _Float16 Bld[2][128 * 64];
    const int tid  = threadIdx.x;
    const int wid  = tid >> 6;            // 0..3
    const int lane = tid & 63;
    const int wm   = wid >> 1, wn = wid & 1;
    const int b    = blockIdx.x >> 3;
    const int n0   = (blockIdx.x & 7) * 128;
    const int co0  = blockIdx.y * 128;

    const _Float16* Ab = A + ((size_t)b * 1024 + n0) * 128;

    const int srow = lane >> 3;
    const int scol = (((lane & 7) ^ (lane >> 3)) << 3);      // pre-swizzled col

    f32x4 acc[4][4] = {};

    // stage both K-tiles: per wave 4 A + 4 B loads per tile (rows 8*(wid+4c))
    #pragma unroll
    for (int ks = 0; ks < 2; ++ks) {
        #pragma unroll
        for (int c = 0; c < 4; ++c) {
            const int grow = 8 * (wid + 4 * c) + srow;
            load_lds16(Ab + (size_t)grow * 128 + ks * 64 + scol, &Ald[ks][(8 * (wid + 4 * c)) * 64]);
        }
        #pragma unroll
        for (int c = 0; c < 4; ++c) {
            const int grow = 8 * (wid + 4 * c) + srow;
            load_lds16(WT + (size_t)(co0 + grow) * 128 + ks * 64 + scol, &Bld[ks][(8 * (wid + 4 * c)) * 64]);
        }
    }

    #pragma unroll
    for (int ks = 0; ks < 2; ++ks) {
        __builtin_amdgcn_sched_barrier(0);
        if (ks == 0) asm volatile("s_waitcnt vmcnt(8)" ::: "memory");
        else         asm volatile("s_waitcnt vmcnt(0)" ::: "memory");
        __builtin_amdgcn_s_barrier();
        __builtin_amdgcn_sched_barrier(0);

        f16x8 af[4][2], bfr[4][2];
        #pragma unroll
        for (int f = 0; f < 4; ++f) {
            const int arow = wm * 64 + f * 16 + (lane & 15);
            const int brow = wn * 64 + f * 16 + (lane & 15);
            #pragma unroll
            for (int kf = 0; kf < 2; ++kf) {
                af[f][kf]  = *(const f16x8*)&Ald[ks][arow * 64 + ((kf * 4 + (lane >> 4)) ^ (arow & 7)) * 8];
                bfr[f][kf] = *(const f16x8*)&Bld[ks][brow * 64 + ((kf * 4 + (lane >> 4)) ^ (brow & 7)) * 8];
            }
        }
        #pragma unroll
        for (int m = 0; m < 4; ++m)
            #pragma unroll
            for (int n = 0; n < 4; ++n)
                #pragma unroll
                for (int kf = 0; kf < 2; ++kf)
                    acc[m][n] = __builtin_amdgcn_mfma_f32_16x16x32_f16(af[m][kf], bfr[n][kf], acc[m][n], 0, 0, 0);
    }

    _Float16* Ob = Out + (size_t)b * (1056 * 512) + (size_t)n0 * 512;
    #pragma unroll
    for (int n = 0; n < 4; ++n) {
        const int co = co0 + wn * 64 + n * 16 + (lane & 15);
        const float bv = bias[co];
        #pragma unroll
        for (int m = 0; m < 4; ++m) {
            #pragma unroll
            for (int j = 0; j < 4; ++j) {
                const int row = wm * 64 + m * 16 + (lane >> 4) * 4 + j;
                float v = acc[m][n][j] + bv;
                v = fmaxf(v, 0.f);
                Ob[(size_t)row * 512 + co] = (_Float16)v;
            }
        }
    }
}

// ---- mid-layer GEMM (r13, unchanged): A-halo reuse, ci-chunk-outer tap-inner,
// A 2x40KB + B 3x16KB = 128KB LDS, derived vmcnt per tap, SGB interleave.
#define ACH_ELEMS (320 * 64)
#define BBUF_ELEMS (128 * 64)
__global__ __launch_bounds__(512, 2)
void conv_gemm8(const _Float16* __restrict__ A, const _Float16* __restrict__ WT,
                const float* __restrict__ bias, _Float16* __restrict__ Out, int dil)
{
    extern __shared__ _Float16 smem[];
    _Float16* Ald = smem;                      // [2][320*64]
    _Float16* Bld = smem + 2 * ACH_ELEMS;      // [3][128*64]

    const int tid  = threadIdx.x;
    const int wid  = tid >> 6;
    const int lane = tid & 63;
    const int wm   = wid >> 1;            // 0..3 : 64-row band
    const int wn   = wid & 1;             // 0..1 : 64-col half

    // XCD-aware bijective swizzle (256 blocks, 256%8==0)
    const int orig = blockIdx.x;
    const int swz  = (orig & 7) * 32 + (orig >> 3);
    const int nblk = swz & 3;
    const int mblk = swz >> 2;
    const int b     = mblk >> 2;
    const int n0row = (mblk & 3) * 256;
    const int co0   = nblk * 128;

    const _Float16* Ab = A + (size_t)b * (1056 * 512) + (size_t)n0row * 512;

    const int srow = lane >> 3;                              // row within 8-row group
    const int scol = (((lane & 7) ^ (lane >> 3)) << 3);      // pre-swizzled global col (f16)

    f32x4 acc[4][4] = {};

    // one A-chunk staging load (i = 0..4): 8-row group (wid + 8i), rows rel. n0row-32
    auto stageA1 = [&](int cn, int i) {
        const int rb = 8 * (wid + 8 * i);                    // 0..312
        const _Float16* src = Ab + (long)(rb + srow - 32) * 512 + cn * 64 + scol;
        load_lds16(src, Ald + (cn & 1) * ACH_ELEMS + rb * 64);
    };
    // one B staging load (cc = 0,1): K-tile (c2, t2) -> buffer t2
    auto stageB1 = [&](int c2, int t2, int cc) {
        const int grow = 64 * cc + 8 * wid + srow;
        const _Float16* src = WT + (size_t)(co0 + grow) * 1536 + (t2 * 512 + c2 * 64) + scol;
        load_lds16(src, Bld + t2 * BBUF_ELEMS + (64 * cc + 8 * wid) * 64);
    };

    // prologue: A(0) x5, B(0,0) x2, B(0,1) x2  -> outstanding [A5,B2,B2]
    stageA1(0, 0); stageA1(0, 1); stageA1(0, 2); stageA1(0, 3); stageA1(0, 4);
    stageB1(0, 0, 0); stageB1(0, 0, 1);
    stageB1(0, 1, 0); stageB1(0, 1, 1);

    auto body = [&](auto TAPc, auto DOAc, int c) {
        constexpr int TAP = decltype(TAPc)::v;
        constexpr int DOA = decltype(DOAc)::v;     // 1 = main chunks (c<7)

        __builtin_amdgcn_sched_barrier(0);
        if constexpr (TAP == 1 && DOA)       asm volatile("s_waitcnt vmcnt(7)" ::: "memory");
        else if constexpr (TAP == 2 && !DOA) asm volatile("s_waitcnt vmcnt(0)" ::: "memory");
        else                                 asm volatile("s_waitcnt vmcnt(2)" ::: "memory");
        __builtin_amdgcn_s_barrier();
        __builtin_amdgcn_sched_barrier(0);

        const _Float16* Abuf = Ald + (c & 1) * ACH_ELEMS;
        const _Float16* Bbuf = Bld + TAP * BBUF_ELEMS;
        const int shift = (TAP - 1) * dil;
        const int rbase = 32 + wm * 64 + (lane & 15) + shift;  // 16|mf*16 keeps key const
        const int akey  = rbase & 7;
        const int bkey  = lane & 7;

        f16x8 bfr[4][2], af[4][2];
        // group: 8 bfr + 2 af[0]
        #pragma unroll
        for (int nf = 0; nf < 4; ++nf) {
            const int row = wn * 64 + nf * 16 + (lane & 15);
            #pragma unroll
            for (int kf = 0; kf < 2; ++kf) {
                const int slot = (kf * 4 + (lane >> 4)) ^ bkey;
                bfr[nf][kf] = *(const f16x8*)&Bbuf[row * 64 + slot * 8];
            }
        }
        #pragma unroll
        for (int kf = 0; kf < 2; ++kf) {
            const int slot = (kf * 4 + (lane >> 4)) ^ akey;
            af[0][kf] = *(const f16x8*)&Abuf[rbase * 64 + slot * 8];
        }
        // mfma mf0
        #pragma unroll
        for (int nf = 0; nf < 4; ++nf)
            #pragma unroll
            for (int kf = 0; kf < 2; ++kf)
                acc[0][nf] = __builtin_amdgcn_mfma_f32_16x16x32_f16(af[0][kf], bfr[nf][kf], acc[0][nf], 0, 0, 0);
        // af1 + stage part1
        #pragma unroll
        for (int kf = 0; kf < 2; ++kf) {
            const int slot = (kf * 4 + (lane >> 4)) ^ akey;
            af[1][kf] = *(const f16x8*)&Abuf[(rbase + 16) * 64 + slot * 8];
        }
        if constexpr (TAP == 0 && DOA) {
            stageA1(c + 1, 0); stageA1(c + 1, 1); stageA1(c + 1, 2); stageA1(c + 1, 3);
        } else if constexpr (TAP == 0) {
            stageB1(7, 2, 0);                    // peeled c=7 tap0: B(23) part1
        } else if constexpr (DOA) {
            if constexpr (TAP == 1) stageB1(c + 1, 0, 0);
            else                    stageB1(c + 1, 1, 0);
        }
        // mfma mf1
        #pragma unroll
        for (int nf = 0; nf < 4; ++nf)
            #pragma unroll
            for (int kf = 0; kf < 2; ++kf)
                acc[1][nf] = __builtin_amdgcn_mfma_f32_16x16x32_f16(af[1][kf], bfr[nf][kf], acc[1][nf], 0, 0, 0);
        // af2 + stage part2
        #pragma unroll
        for (int kf = 0; kf < 2; ++kf) {
            const int slot = (kf * 4 + (lane >> 4)) ^ akey;
            af[2][kf] = *(const f16x8*)&Abuf[(rbase + 32) * 64 + slot * 8];
        }
        if constexpr (TAP == 0 && DOA) {
            stageA1(c + 1, 4);
            stageB1(c, 2, 0); stageB1(c, 2, 1);  // B(3c+2)
        } else if constexpr (TAP == 0) {
            stageB1(7, 2, 1);                    // peeled: B(23) part2
        } else if constexpr (DOA) {
            if constexpr (TAP == 1) stageB1(c + 1, 0, 1);
            else                    stageB1(c + 1, 1, 1);
        }
        // mfma mf2
        #pragma unroll
        for (int nf = 0; nf < 4; ++nf)
            #pragma unroll
            for (int kf = 0; kf < 2; ++kf)
                acc[2][nf] = __builtin_amdgcn_mfma_f32_16x16x32_f16(af[2][kf], bfr[nf][kf], acc[2][nf], 0, 0, 0);
        // af3
        #pragma unroll
        for (int kf = 0; kf < 2; ++kf) {
            const int slot = (kf * 4 + (lane >> 4)) ^ akey;
            af[3][kf] = *(const f16x8*)&Abuf[(rbase + 48) * 64 + slot * 8];
        }
        // mfma mf3
        #pragma unroll
        for (int nf = 0; nf < 4; ++nf)
            #pragma unroll
            for (int kf = 0; kf < 2; ++kf)
                acc[3][nf] = __builtin_amdgcn_mfma_f32_16x16x32_f16(af[3][kf], bfr[nf][kf], acc[3][nf], 0, 0, 0);

        if constexpr (DOA) {
            if constexpr (TAP == 0) {
                __builtin_amdgcn_sched_group_barrier(0x100, 10, 0);
                __builtin_amdgcn_sched_group_barrier(0x008,  8, 0);
                __builtin_amdgcn_sched_group_barrier(0x100,  2, 0);
                __builtin_amdgcn_sched_group_barrier(0x070,  4, 0);
                __builtin_amdgcn_sched_group_barrier(0x008,  8, 0);
                __builtin_amdgcn_sched_group_barrier(0x100,  2, 0);
                __builtin_amdgcn_sched_group_barrier(0x070,  3, 0);
                __builtin_amdgcn_sched_group_barrier(0x008,  8, 0);
                __builtin_amdgcn_sched_group_barrier(0x100,  2, 0);
                __builtin_amdgcn_sched_group_barrier(0x008,  8, 0);
            } else {
                __builtin_amdgcn_sched_group_barrier(0x100, 10, 0);
                __builtin_amdgcn_sched_group_barrier(0x008,  8, 0);
                __builtin_amdgcn_sched_group_barrier(0x100,  2, 0);
                __builtin_amdgcn_sched_group_barrier(0x070,  1, 0);
                __builtin_amdgcn_sched_group_barrier(0x008,  8, 0);
                __builtin_amdgcn_sched_group_barrier(0x100,  2, 0);
                __builtin_amdgcn_sched_group_barrier(0x070,  1, 0);
                __builtin_amdgcn_sched_group_barrier(0x008,  8, 0);
                __builtin_amdgcn_sched_group_barrier(0x100,  2, 0);
                __builtin_amdgcn_sched_group_barrier(0x008,  8, 0);
            }
        }
    };

    #pragma unroll 1
    for (int c = 0; c < 7; ++c) {
        body(IC<0>{}, IC<1>{}, c);
        body(IC<1>{}, IC<1>{}, c);
        body(IC<2>{}, IC<1>{}, c);
    }
    body(IC<0>{}, IC<0>{}, 7);
    body(IC<1>{}, IC<0>{}, 7);
    body(IC<2>{}, IC<0>{}, 7);

    _Float16* Ob = Out + (size_t)b * (1056 * 512) + (size_t)n0row * 512;
    #pragma unroll
    for (int nf = 0; nf < 4; ++nf) {
        const int co = co0 + wn * 64 + nf * 16 + (lane & 15);
        const float bv = bias[co];
        #pragma unroll
        for (int m = 0; m < 4; ++m) {
            #pragma unroll
            for (int j = 0; j < 4; ++j) {
                const int row = wm * 64 + m * 16 + (lane >> 4) * 4 + j;
                float v = acc[m][nf][j] + bv;
                v = fmaxf(v, 0.f);
                Ob[(size_t)row * 512 + co] = (_Float16)v;
            }
        }
    }
}

// ---- final 1x1 conv to 2 channels, fp32 out. One wave per row.
__global__ __launch_bounds__(256)
void final_conv(const _Float16* __restrict__ Y, const float* __restrict__ woff,
                float* __restrict__ out)
{
    const int r = blockIdx.x * 4 + (threadIdx.x >> 6);  // 0..16383
    const int lane = threadIdx.x & 63;
    const int b = r >> 10, n = r & 1023;
    const _Float16* yp = Y + ((size_t)b * 1056 + n) * 512 + lane * 8;
    f16x8 yv = *(const f16x8*)yp;
    const int ci0 = lane * 8;
    float s0 = 0.f, s1 = 0.f;
    #pragma unroll
    for (int e = 0; e < 8; ++e) {
        float y = (float)yv[e];
        s0 += y * woff[(ci0 + e) * 2 + 0];
        s1 += y * woff[(ci0 + e) * 2 + 1];
    }
    #pragma unroll
    for (int off = 32; off; off >>= 1) {
        s0 += __shfl_down(s0, off);
        s1 += __shfl_down(s1, off);
    }
    if (lane == 0) { out[r*2] = s0; out[r*2 + 1] = s1; }
}

extern "C" void kernel_launch(void* const* d_in, const int* in_sizes, int n_in,
                              void* d_out, int out_size, void* d_ws, size_t ws_size,
                              hipStream_t stream)
{
    const float* verts = (const float*)d_in[0];
    const float* fm    = (const float*)d_in[1];
    const float* w0    = (const float*)d_in[2];
    const float* b0    = (const float*)d_in[3];
    const float* ws    = (const float*)d_in[4];
    const float* bs    = (const float*)d_in[5];
    const float* woff  = (const float*)d_in[6];
    float* out = (float*)d_out;

    char* wsp = (char*)d_ws;
    _Float16* W0T = (_Float16*)(wsp + OFF_W0T);
    _Float16* WT  = (_Float16*)(wsp + OFF_WT);
    _Float16* X0  = (_Float16*)(wsp + OFF_X0);
    _Float16* Y0  = (_Float16*)(wsp + OFF_Y0);
    _Float16* Y1  = (_Float16*)(wsp + OFF_Y1);
    _Float16* Y0i = Y0 + 16 * 512;   // interior (row 0 of batch 0)
    _Float16* Y1i = Y1 + 16 * 512;

    hipFuncSetAttribute(reinterpret_cast<const void*>(&conv_gemm8),
                        hipFuncAttributeMaxDynamicSharedMemorySize, 131072);

    wprep<<<dim3(8, 8, 19), 256, 0, stream>>>(ws, w0, WT, W0T);
    sample_pad_kernel<<<5120, 256, 0, stream>>>(verts, fm, X0, Y0, Y1);

    // layer 0: 1x1 conv, K=128 (r14 structure)
    conv_gemm0<<<dim3(128, 4), 256, 0, stream>>>(X0, W0T, b0, Y0i);

    // 6 dilated mid layers, K=1536, r13 kernel
    const int DIL[6] = {1, 3, 9, 9, 3, 1};
    _Float16* bufs[2] = {Y0i, Y1i};
    for (int l = 0; l < 6; ++l) {
        conv_gemm8<<<256, 512, 131072, stream>>>(
            bufs[l & 1],
            WT + (size_t)l * 512 * 1536, bs + (size_t)l * 512,
            bufs[(l + 1) & 1], DIL[l]);
    }

    // final projection (reads Y0i after 6 layers)
    final_conv<<<4096, 256, 0, stream>>>(bufs[0], woff, out);
}

// Round 15
// 170.103 us; speedup vs baseline: 2.5971x; 1.0352x over previous
//
#include <hip/hip_runtime.h>

typedef __attribute__((ext_vector_type(4))) float f32x4;
typedef __attribute__((ext_vector_type(8))) _Float16 f16x8;

// workspace layout (bytes)
#define OFF_W0T 0                                   // 512*128*2   = 131072
#define OFF_WT  131072                              // 6*512*1536*2 = 9437184
#define OFF_X0  (OFF_WT + 6*512*1536*2)             // 16384*128*2 = 4194304
#define OFF_Y0  (OFF_X0 + 16384*128*2)              // 16*1056*512*2
#define OFF_Y1  (OFF_Y0 + 16*1056*512*2)

__device__ __forceinline__ void load_lds16(const void* g, void* s) {
    __builtin_amdgcn_global_load_lds(
        (const __attribute__((address_space(1))) void*)g,
        (__attribute__((address_space(3))) void*)s, 16, 0, 0);
}

template<int N> struct IC { static constexpr int v = N; };

// ---- fused prep kernel:
//  blocks [0,1216):    weight prep (ws -> wt, w0 -> w0t)
//  blocks [1216,2240): zero 16-row pads of Y0/Y1
//  blocks [2240,2272): zero d_out (32768 f32)
//  blocks [2272,6368): bilinear sample + concat -> X0
__global__ __launch_bounds__(256)
void prep(const float* __restrict__ ws, const float* __restrict__ w0,
          _Float16* __restrict__ wt, _Float16* __restrict__ w0t,
          const float* __restrict__ verts, const float* __restrict__ fm,
          _Float16* __restrict__ X0, _Float16* __restrict__ Y0,
          _Float16* __restrict__ Y1, float* __restrict__ outp)
{
    __shared__ float t[64][65];
    const int bid = blockIdx.x;
    const int tid = threadIdx.x;
    if (bid < 1216) {
        const int z   = bid >> 6;
        const int rem = bid & 63;
        const int bx  = rem & 7;
        const int by  = rem >> 3;
        const int tr = tid >> 6;       // 0..3
        const int tc = tid & 63;
        if (z < 18) {
            const int l = z / 3, tp = z % 3;
            const float* src = ws + (size_t)z * 512 * 512;      // [ci][co]
            const int ci0 = by * 64, co0 = bx * 64;
            #pragma unroll
            for (int i = 0; i < 16; ++i) { int r = i*4 + tr; t[r][tc] = src[(ci0 + r)*512 + co0 + tc]; }
            __syncthreads();
            _Float16* dst = wt + (size_t)l * 512 * 1536;
            #pragma unroll
            for (int i = 0; i < 16; ++i) { int r = i*4 + tr; dst[(co0 + r)*1536 + tp*512 + ci0 + tc] = (_Float16)t[tc][r]; }
        } else {
            if (by >= 2) return;
            const int ci0 = by * 64, co0 = bx * 64;
            #pragma unroll
            for (int i = 0; i < 16; ++i) { int r = i*4 + tr; t[r][tc] = w0[(ci0 + r)*512 + co0 + tc]; }
            __syncthreads();
            #pragma unroll
            for (int i = 0; i < 16; ++i) { int r = i*4 + tr; w0t[(co0 + r)*128 + ci0 + tc] = (_Float16)t[tc][r]; }
        }
        return;
    }
    if (bid < 2240) {
        const int i = (bid - 1216) * 256 + tid;             // 262144 total
        const unsigned c2   = i & 255;                      // u32 col (512 f16 / row)
        const unsigned t2   = ((unsigned)i) >> 8;
        const unsigned prow = t2 & 31;
        const unsigned b    = (t2 >> 5) & 15;
        const unsigned buf  = t2 >> 9;
        const unsigned row  = prow < 16 ? prow : (1024 + prow); // [0,16) and [1040,1056)
        unsigned* p = (unsigned*)(buf ? Y1 : Y0);
        p[((size_t)b * 1056 + row) * 256 + c2] = 0u;
        return;
    }
    if (bid < 2272) {
        const int i = (bid - 2240) * 256 + tid;             // 8192 float4s
        *(f32x4*)&outp[i * 4] = f32x4{0.f, 0.f, 0.f, 0.f};
        return;
    }
    const int p = (bid - 2272) * 4 + (tid >> 6);            // 0..16383
    const int lane = tid & 63;
    const int b = p >> 10;
    const float vy = verts[p*2], vx = verts[p*2 + 1];
    const float cy = (vy + 1.f) * 127.5f;
    const float cx = (vx + 1.f) * 127.5f;
    const float fy = floorf(cy), fx = floorf(cx);
    const int y0 = (int)fy, x0 = (int)fx;
    const float wy = cy - fy, wx = cx - fx;
    float w00 = (1.f - wy) * (1.f - wx), w01 = (1.f - wy) * wx;
    float w10 = wy * (1.f - wx),         w11 = wy * wx;
    const bool vy0 = (unsigned)y0 < 256u, vy1 = (unsigned)(y0 + 1) < 256u;
    const bool vx0 = (unsigned)x0 < 256u, vx1 = (unsigned)(x0 + 1) < 256u;
    w00 = (vy0 && vx0) ? w00 : 0.f;
    w01 = (vy0 && vx1) ? w01 : 0.f;
    w10 = (vy1 && vx0) ? w10 : 0.f;
    w11 = (vy1 && vx1) ? w11 : 0.f;
    const int yc0 = min(max(y0, 0), 255), yc1 = min(max(y0 + 1, 0), 255);
    const int xc0 = min(max(x0, 0), 255), xc1 = min(max(x0 + 1, 0), 255);
    const float* base = fm + (size_t)b * (256 * 256 * 126);
    const float* p00 = base + (yc0 * 256 + xc0) * 126;
    const float* p01 = base + (yc0 * 256 + xc1) * 126;
    const float* p10 = base + (yc1 * 256 + xc0) * 126;
    const float* p11 = base + (yc1 * 256 + xc1) * 126;
    _Float16* xr = X0 + (size_t)p * 128;
    for (int c = lane; c < 126; c += 64) {
        float a = w00 * p00[c] + w01 * p01[c] + w10 * p10[c] + w11 * p11[c];
        xr[c] = (_Float16)a;
    }
    if (lane < 2) xr[126 + lane] = (_Float16)(lane ? vx : vy);
}

// ---- layer-0 GEMM (r14): K=128, both K-tiles prefetched, counted vmcnt,
// one barrier per K-tile, T2 swizzle. Block 128x128, 4 waves 2Mx2N.
__global__ __launch_bounds__(256, 2)
void conv_gemm0(const _Float16* __restrict__ A, const _Float16* __restrict__ WT,
                const float* __restrict__ bias, _Float16* __restrict__ Out)
{
    __shared__ _Float16 Ald[2][128 * 64];
    __shared__ _Float16 Bld[2][128 * 64];
    const int tid  = threadIdx.x;
    const int wid  = tid >> 6;            // 0..3
    const int lane = tid & 63;
    const int wm   = wid >> 1, wn = wid & 1;
    const int b    = blockIdx.x >> 3;
    const int n0   = (blockIdx.x & 7) * 128;
    const int co0  = blockIdx.y * 128;

    const _Float16* Ab = A + ((size_t)b * 1024 + n0) * 128;

    const int srow = lane >> 3;
    const int scol = (((lane & 7) ^ (lane >> 3)) << 3);      // pre-swizzled col

    f32x4 acc[4][4] = {};

    #pragma unroll
    for (int ks = 0; ks < 2; ++ks) {
        #pragma unroll
        for (int c = 0; c < 4; ++c) {
            const int grow = 8 * (wid + 4 * c) + srow;
            load_lds16(Ab + (size_t)grow * 128 + ks * 64 + scol, &Ald[ks][(8 * (wid + 4 * c)) * 64]);
        }
        #pragma unroll
        for (int c = 0; c < 4; ++c) {
            const int grow = 8 * (wid + 4 * c) + srow;
            load_lds16(WT + (size_t)(co0 + grow) * 128 + ks * 64 + scol, &Bld[ks][(8 * (wid + 4 * c)) * 64]);
        }
    }

    #pragma unroll
    for (int ks = 0; ks < 2; ++ks) {
        __builtin_amdgcn_sched_barrier(0);
        if (ks == 0) asm volatile("s_waitcnt vmcnt(8)" ::: "memory");
        else         asm volatile("s_waitcnt vmcnt(0)" ::: "memory");
        __builtin_amdgcn_s_barrier();
        __builtin_amdgcn_sched_barrier(0);

        f16x8 af[4][2], bfr[4][2];
        #pragma unroll
        for (int f = 0; f < 4; ++f) {
            const int arow = wm * 64 + f * 16 + (lane & 15);
            const int brow = wn * 64 + f * 16 + (lane & 15);
            #pragma unroll
            for (int kf = 0; kf < 2; ++kf) {
                af[f][kf]  = *(const f16x8*)&Ald[ks][arow * 64 + ((kf * 4 + (lane >> 4)) ^ (arow & 7)) * 8];
                bfr[f][kf] = *(const f16x8*)&Bld[ks][brow * 64 + ((kf * 4 + (lane >> 4)) ^ (brow & 7)) * 8];
            }
        }
        #pragma unroll
        for (int m = 0; m < 4; ++m)
            #pragma unroll
            for (int n = 0; n < 4; ++n)
                #pragma unroll
                for (int kf = 0; kf < 2; ++kf)
                    acc[m][n] = __builtin_amdgcn_mfma_f32_16x16x32_f16(af[m][kf], bfr[n][kf], acc[m][n], 0, 0, 0);
    }

    _Float16* Ob = Out + (size_t)b * (1056 * 512) + (size_t)n0 * 512;
    #pragma unroll
    for (int n = 0; n < 4; ++n) {
        const int co = co0 + wn * 64 + n * 16 + (lane & 15);
        const float bv = bias[co];
        #pragma unroll
        for (int m = 0; m < 4; ++m) {
            #pragma unroll
            for (int j = 0; j < 4; ++j) {
                const int row = wm * 64 + m * 16 + (lane >> 4) * 4 + j;
                float v = acc[m][n][j] + bv;
                v = fmaxf(v, 0.f);
                Ob[(size_t)row * 512 + co] = (_Float16)v;
            }
        }
    }
}

// ---- mid-layer GEMM (r13 structure): A-halo reuse, ci-chunk-outer tap-inner,
// A 2x40KB + B 3x16KB = 128KB LDS, derived vmcnt per tap, SGB interleave.
// FUSE=1 (last layer): project to 2 channels with woff, shfl-reduce, atomicAdd
// into zeroed d_out; skip the Y write.
#define ACH_ELEMS (320 * 64)
#define BBUF_ELEMS (128 * 64)
template<int FUSE>
__global__ __launch_bounds__(512, 2)
void conv_gemm8(const _Float16* __restrict__ A, const _Float16* __restrict__ WT,
                const float* __restrict__ bias, _Float16* __restrict__ Out, int dil,
                const float* __restrict__ woff, float* __restrict__ outp)
{
    extern __shared__ _Float16 smem[];
    _Float16* Ald = smem;                      // [2][320*64]
    _Float16* Bld = smem + 2 * ACH_ELEMS;      // [3][128*64]

    const int tid  = threadIdx.x;
    const int wid  = tid >> 6;
    const int lane = tid & 63;
    const int wm   = wid >> 1;            // 0..3 : 64-row band
    const int wn   = wid & 1;             // 0..1 : 64-col half

    // XCD-aware bijective swizzle (256 blocks, 256%8==0)
    const int orig = blockIdx.x;
    const int swz  = (orig & 7) * 32 + (orig >> 3);
    const int nblk = swz & 3;
    const int mblk = swz >> 2;
    const int b     = mblk >> 2;
    const int n0row = (mblk & 3) * 256;
    const int co0   = nblk * 128;

    const _Float16* Ab = A + (size_t)b * (1056 * 512) + (size_t)n0row * 512;

    const int srow = lane >> 3;                              // row within 8-row group
    const int scol = (((lane & 7) ^ (lane >> 3)) << 3);      // pre-swizzled global col (f16)

    f32x4 acc[4][4] = {};

    auto stageA1 = [&](int cn, int i) {
        const int rb = 8 * (wid + 8 * i);                    // 0..312
        const _Float16* src = Ab + (long)(rb + srow - 32) * 512 + cn * 64 + scol;
        load_lds16(src, Ald + (cn & 1) * ACH_ELEMS + rb * 64);
    };
    auto stageB1 = [&](int c2, int t2, int cc) {
        const int grow = 64 * cc + 8 * wid + srow;
        const _Float16* src = WT + (size_t)(co0 + grow) * 1536 + (t2 * 512 + c2 * 64) + scol;
        load_lds16(src, Bld + t2 * BBUF_ELEMS + (64 * cc + 8 * wid) * 64);
    };

    // prologue: A(0) x5, B(0,0) x2, B(0,1) x2  -> outstanding [A5,B2,B2]
    stageA1(0, 0); stageA1(0, 1); stageA1(0, 2); stageA1(0, 3); stageA1(0, 4);
    stageB1(0, 0, 0); stageB1(0, 0, 1);
    stageB1(0, 1, 0); stageB1(0, 1, 1);

    auto body = [&](auto TAPc, auto DOAc, int c) {
        constexpr int TAP = decltype(TAPc)::v;
        constexpr int DOA = decltype(DOAc)::v;     // 1 = main chunks (c<7)

        __builtin_amdgcn_sched_barrier(0);
        if constexpr (TAP == 1 && DOA)       asm volatile("s_waitcnt vmcnt(7)" ::: "memory");
        else if constexpr (TAP == 2 && !DOA) asm volatile("s_waitcnt vmcnt(0)" ::: "memory");
        else                                 asm volatile("s_waitcnt vmcnt(2)" ::: "memory");
        __builtin_amdgcn_s_barrier();
        __builtin_amdgcn_sched_barrier(0);

        const _Float16* Abuf = Ald + (c & 1) * ACH_ELEMS;
        const _Float16* Bbuf = Bld + TAP * BBUF_ELEMS;
        const int shift = (TAP - 1) * dil;
        const int rbase = 32 + wm * 64 + (lane & 15) + shift;  // 16|mf*16 keeps key const
        const int akey  = rbase & 7;
        const int bkey  = lane & 7;

        f16x8 bfr[4][2], af[4][2];
        #pragma unroll
        for (int nf = 0; nf < 4; ++nf) {
            const int row = wn * 64 + nf * 16 + (lane & 15);
            #pragma unroll
            for (int kf = 0; kf < 2; ++kf) {
                const int slot = (kf * 4 + (lane >> 4)) ^ bkey;
                bfr[nf][kf] = *(const f16x8*)&Bbuf[row * 64 + slot * 8];
            }
        }
        #pragma unroll
        for (int kf = 0; kf < 2; ++kf) {
            const int slot = (kf * 4 + (lane >> 4)) ^ akey;
            af[0][kf] = *(const f16x8*)&Abuf[rbase * 64 + slot * 8];
        }
        #pragma unroll
        for (int nf = 0; nf < 4; ++nf)
            #pragma unroll
            for (int kf = 0; kf < 2; ++kf)
                acc[0][nf] = __builtin_amdgcn_mfma_f32_16x16x32_f16(af[0][kf], bfr[nf][kf], acc[0][nf], 0, 0, 0);
        #pragma unroll
        for (int kf = 0; kf < 2; ++kf) {
            const int slot = (kf * 4 + (lane >> 4)) ^ akey;
            af[1][kf] = *(const f16x8*)&Abuf[(rbase + 16) * 64 + slot * 8];
        }
        if constexpr (TAP == 0 && DOA) {
            stageA1(c + 1, 0); stageA1(c + 1, 1); stageA1(c + 1, 2); stageA1(c + 1, 3);
        } else if constexpr (TAP == 0) {
            stageB1(7, 2, 0);                    // peeled c=7 tap0: B(23) part1
        } else if constexpr (DOA) {
            if constexpr (TAP == 1) stageB1(c + 1, 0, 0);
            else                    stageB1(c + 1, 1, 0);
        }
        #pragma unroll
        for (int nf = 0; nf < 4; ++nf)
            #pragma unroll
            for (int kf = 0; kf < 2; ++kf)
                acc[1][nf] = __builtin_amdgcn_mfma_f32_16x16x32_f16(af[1][kf], bfr[nf][kf], acc[1][nf], 0, 0, 0);
        #pragma unroll
        for (int kf = 0; kf < 2; ++kf) {
            const int slot = (kf * 4 + (lane >> 4)) ^ akey;
            af[2][kf] = *(const f16x8*)&Abuf[(rbase + 32) * 64 + slot * 8];
        }
        if constexpr (TAP == 0 && DOA) {
            stageA1(c + 1, 4);
            stageB1(c, 2, 0); stageB1(c, 2, 1);  // B(3c+2)
        } else if constexpr (TAP == 0) {
            stageB1(7, 2, 1);                    // peeled: B(23) part2
        } else if constexpr (DOA) {
            if constexpr (TAP == 1) stageB1(c + 1, 0, 1);
            else                    stageB1(c + 1, 1, 1);
        }
        #pragma unroll
        for (int nf = 0; nf < 4; ++nf)
            #pragma unroll
            for (int kf = 0; kf < 2; ++kf)
                acc[2][nf] = __builtin_amdgcn_mfma_f32_16x16x32_f16(af[2][kf], bfr[nf][kf], acc[2][nf], 0, 0, 0);
        #pragma unroll
        for (int kf = 0; kf < 2; ++kf) {
            const int slot = (kf * 4 + (lane >> 4)) ^ akey;
            af[3][kf] = *(const f16x8*)&Abuf[(rbase + 48) * 64 + slot * 8];
        }
        #pragma unroll
        for (int nf = 0; nf < 4; ++nf)
            #pragma unroll
            for (int kf = 0; kf < 2; ++kf)
                acc[3][nf] = __builtin_amdgcn_mfma_f32_16x16x32_f16(af[3][kf], bfr[nf][kf], acc[3][nf], 0, 0, 0);

        if constexpr (DOA) {
            if constexpr (TAP == 0) {
                __builtin_amdgcn_sched_group_barrier(0x100, 10, 0);
                __builtin_amdgcn_sched_group_barrier(0x008,  8, 0);
                __builtin_amdgcn_sched_group_barrier(0x100,  2, 0);
                __builtin_amdgcn_sched_group_barrier(0x070,  4, 0);
                __builtin_amdgcn_sched_group_barrier(0x008,  8, 0);
                __builtin_amdgcn_sched_group_barrier(0x100,  2, 0);
                __builtin_amdgcn_sched_group_barrier(0x070,  3, 0);
                __builtin_amdgcn_sched_group_barrier(0x008,  8, 0);
                __builtin_amdgcn_sched_group_barrier(0x100,  2, 0);
                __builtin_amdgcn_sched_group_barrier(0x008,  8, 0);
            } else {
                __builtin_amdgcn_sched_group_barrier(0x100, 10, 0);
                __builtin_amdgcn_sched_group_barrier(0x008,  8, 0);
                __builtin_amdgcn_sched_group_barrier(0x100,  2, 0);
                __builtin_amdgcn_sched_group_barrier(0x070,  1, 0);
                __builtin_amdgcn_sched_group_barrier(0x008,  8, 0);
                __builtin_amdgcn_sched_group_barrier(0x100,  2, 0);
                __builtin_amdgcn_sched_group_barrier(0x070,  1, 0);
                __builtin_amdgcn_sched_group_barrier(0x008,  8, 0);
                __builtin_amdgcn_sched_group_barrier(0x100,  2, 0);
                __builtin_amdgcn_sched_group_barrier(0x008,  8, 0);
            }
        }
    };

    #pragma unroll 1
    for (int c = 0; c < 7; ++c) {
        body(IC<0>{}, IC<1>{}, c);
        body(IC<1>{}, IC<1>{}, c);
        body(IC<2>{}, IC<1>{}, c);
    }
    body(IC<0>{}, IC<0>{}, 7);
    body(IC<1>{}, IC<0>{}, 7);
    body(IC<2>{}, IC<0>{}, 7);

    float bv[4], w0v[4], w1v[4];
    #pragma unroll
    for (int nf = 0; nf < 4; ++nf) {
        const int co = co0 + wn * 64 + nf * 16 + (lane & 15);
        bv[nf] = bias[co];
        if constexpr (FUSE) { w0v[nf] = woff[co * 2 + 0]; w1v[nf] = woff[co * 2 + 1]; }
    }
    if constexpr (FUSE) {
        #pragma unroll
        for (int m = 0; m < 4; ++m) {
            #pragma unroll
            for (int j = 0; j < 4; ++j) {
                float s0 = 0.f, s1 = 0.f;
                #pragma unroll
                for (int nf = 0; nf < 4; ++nf) {
                    float v = fmaxf(acc[m][nf][j] + bv[nf], 0.f);
                    float vf = (float)(_Float16)v;   // match reference's f16 round-trip
                    s0 += vf * w0v[nf];
                    s1 += vf * w1v[nf];
                }
                #pragma unroll
                for (int off = 1; off < 16; off <<= 1) {
                    s0 += __shfl_xor(s0, off);
                    s1 += __shfl_xor(s1, off);
                }
                if ((lane & 15) == 0) {
                    const int r = b * 1024 + n0row + wm * 64 + m * 16 + (lane >> 4) * 4 + j;
                    atomicAdd(&outp[r * 2 + 0], s0);
                    atomicAdd(&outp[r * 2 + 1], s1);
                }
            }
        }
    } else {
        _Float16* Ob = Out + (size_t)b * (1056 * 512) + (size_t)n0row * 512;
        #pragma unroll
        for (int nf = 0; nf < 4; ++nf) {
            const int co = co0 + wn * 64 + nf * 16 + (lane & 15);
            #pragma unroll
            for (int m = 0; m < 4; ++m) {
                #pragma unroll
                for (int j = 0; j < 4; ++j) {
                    const int row = wm * 64 + m * 16 + (lane >> 4) * 4 + j;
                    float v = acc[m][nf][j] + bv[nf];
                    v = fmaxf(v, 0.f);
                    Ob[(size_t)row * 512 + co] = (_Float16)v;
                }
            }
        }
    }
}

extern "C" void kernel_launch(void* const* d_in, const int* in_sizes, int n_in,
                              void* d_out, int out_size, void* d_ws, size_t ws_size,
                              hipStream_t stream)
{
    const float* verts = (const float*)d_in[0];
    const float* fm    = (const float*)d_in[1];
    const float* w0    = (const float*)d_in[2];
    const float* b0    = (const float*)d_in[3];
    const float* ws    = (const float*)d_in[4];
    const float* bs    = (const float*)d_in[5];
    const float* woff  = (const float*)d_in[6];
    float* out = (float*)d_out;

    char* wsp = (char*)d_ws;
    _Float16* W0T = (_Float16*)(wsp + OFF_W0T);
    _Float16* WT  = (_Float16*)(wsp + OFF_WT);
    _Float16* X0  = (_Float16*)(wsp + OFF_X0);
    _Float16* Y0  = (_Float16*)(wsp + OFF_Y0);
    _Float16* Y1  = (_Float16*)(wsp + OFF_Y1);
    _Float16* Y0i = Y0 + 16 * 512;   // interior (row 0 of batch 0)
    _Float16* Y1i = Y1 + 16 * 512;

    hipFuncSetAttribute(reinterpret_cast<const void*>(&conv_gemm8<0>),
                        hipFuncAttributeMaxDynamicSharedMemorySize, 131072);
    hipFuncSetAttribute(reinterpret_cast<const void*>(&conv_gemm8<1>),
                        hipFuncAttributeMaxDynamicSharedMemorySize, 131072);

    // fused prep: weights + pad-zero + out-zero + sampling
    prep<<<6368, 256, 0, stream>>>(ws, w0, WT, W0T, verts, fm, X0, Y0, Y1, out);

    // layer 0: 1x1 conv, K=128
    conv_gemm0<<<dim3(128, 4), 256, 0, stream>>>(X0, W0T, b0, Y0i);

    // 6 dilated mid layers, K=1536; last layer fuses the output projection
    const int DIL[6] = {1, 3, 9, 9, 3, 1};
    _Float16* bufs[2] = {Y0i, Y1i};
    for (int l = 0; l < 5; ++l) {
        conv_gemm8<0><<<256, 512, 131072, stream>>>(
            bufs[l & 1],
            WT + (size_t)l * 512 * 1536, bs + (size_t)l * 512,
            bufs[(l + 1) & 1], DIL[l], woff, out);
    }
    conv_gemm8<1><<<256, 512, 131072, stream>>>(
        bufs[1],                                   // l=5 input (l odd)
        WT + (size_t)5 * 512 * 1536, bs + (size_t)5 * 512,
        bufs[0], DIL[5], woff, out);
}